// Round 1
// baseline (449.725 us; speedup 1.0000x reference)
//
#include <hip/hip_runtime.h>
#include <math.h>

#define NBATCH 32768
#define IND    784
#define HIDD   256
#define OUTD   1000

__device__ __forceinline__ float wave_allreduce_sum(float v) {
    #pragma unroll
    for (int off = 32; off >= 1; off >>= 1) v += __shfl_xor(v, off);
    return v;
}

// ---------------- GEMM: C[M,N] = op(A)[M,K] * Bw[N,K]^T + bias ----------------
// op(A) = FUSE ? relu(A*sA[k] + tA[k]) : A   (per-k-column affine, for fused BN2)
template<bool FUSE, bool NCHK>
__global__ __launch_bounds__(256, 2)
void gemm_tn(const float* __restrict__ A, const float* __restrict__ Bw,
             const float* __restrict__ bias,
             const float* __restrict__ sA, const float* __restrict__ tA,
             float* __restrict__ C, int M, int N, int K, int nbn)
{
    __shared__ __align__(16) float As[16][132];
    __shared__ __align__(16) float Bs[16][132];
    const int bid = blockIdx.x;
    const int bm = bid / nbn, bn = bid % nbn;
    const int m0 = bm * 128, n0 = bn * 128;
    const int tid = threadIdx.x;
    const int ty = tid >> 4, tx = tid & 15;

    float acc[8][8];
    #pragma unroll
    for (int i = 0; i < 8; ++i)
        #pragma unroll
        for (int j = 0; j < 8; ++j) acc[i][j] = 0.0f;

    const int lrow = tid >> 2;         // 0..63
    const int kv   = (tid & 3) * 4;    // 0,4,8,12

    for (int k0 = 0; k0 < K; k0 += 16) {
        #pragma unroll
        for (int l = 0; l < 2; ++l) {
            const int r = lrow + l * 64;    // 0..127
            // A tile
            float4 va = *reinterpret_cast<const float4*>(&A[(size_t)(m0 + r) * K + k0 + kv]);
            float av[4] = {va.x, va.y, va.z, va.w};
            #pragma unroll
            for (int j = 0; j < 4; ++j) {
                float xv = av[j];
                if (FUSE) {
                    const int k = k0 + kv + j;
                    xv = fmaxf(fmaf(xv, sA[k], tA[k]), 0.0f);
                }
                As[kv + j][r] = xv;
            }
            // B tile
            float4 vb;
            if (!NCHK || (n0 + r) < N)
                vb = *reinterpret_cast<const float4*>(&Bw[(size_t)(n0 + r) * K + k0 + kv]);
            else
                vb = make_float4(0.f, 0.f, 0.f, 0.f);
            float bvv[4] = {vb.x, vb.y, vb.z, vb.w};
            #pragma unroll
            for (int j = 0; j < 4; ++j) Bs[kv + j][r] = bvv[j];
        }
        __syncthreads();
        #pragma unroll
        for (int kk = 0; kk < 16; ++kk) {
            float a[8], b[8];
            *reinterpret_cast<float4*>(&a[0]) = *reinterpret_cast<const float4*>(&As[kk][ty * 8]);
            *reinterpret_cast<float4*>(&a[4]) = *reinterpret_cast<const float4*>(&As[kk][ty * 8 + 4]);
            *reinterpret_cast<float4*>(&b[0]) = *reinterpret_cast<const float4*>(&Bs[kk][tx * 8]);
            *reinterpret_cast<float4*>(&b[4]) = *reinterpret_cast<const float4*>(&Bs[kk][tx * 8 + 4]);
            #pragma unroll
            for (int i = 0; i < 8; ++i)
                #pragma unroll
                for (int j = 0; j < 8; ++j)
                    acc[i][j] = fmaf(a[i], b[j], acc[i][j]);
        }
        __syncthreads();
    }

    // epilogue
    float bv[8];
    #pragma unroll
    for (int j = 0; j < 8; ++j) {
        const int col = n0 + tx * 8 + j;
        bv[j] = (!NCHK || col < N) ? bias[col] : 0.0f;
    }
    if (!NCHK || n0 + 128 <= N) {
        #pragma unroll
        for (int i = 0; i < 8; ++i) {
            const size_t base = (size_t)(m0 + ty * 8 + i) * N + n0 + tx * 8;
            float4 o0 = make_float4(acc[i][0] + bv[0], acc[i][1] + bv[1],
                                    acc[i][2] + bv[2], acc[i][3] + bv[3]);
            float4 o1 = make_float4(acc[i][4] + bv[4], acc[i][5] + bv[5],
                                    acc[i][6] + bv[6], acc[i][7] + bv[7]);
            *reinterpret_cast<float4*>(&C[base])     = o0;
            *reinterpret_cast<float4*>(&C[base + 4]) = o1;
        }
    } else {
        #pragma unroll
        for (int i = 0; i < 8; ++i) {
            const int r = m0 + ty * 8 + i;
            #pragma unroll
            for (int j = 0; j < 8; ++j) {
                const int col = n0 + tx * 8 + j;
                if (col < N) C[(size_t)r * N + col] = acc[i][j] + bv[j];
            }
        }
    }
}

// ---------------- BN1 stats: per-column sum / sumsq over h[NBATCH][256] ----------------
__global__ __launch_bounds__(256)
void bn_stats(const float* __restrict__ h, float* __restrict__ sum, float* __restrict__ ssq)
{
    const int tid = threadIdx.x;
    const int row0 = blockIdx.x * 128;
    float s = 0.f, q = 0.f;
    for (int r = 0; r < 128; ++r) {
        float v = h[(size_t)(row0 + r) * HIDD + tid];
        s += v;
        q += v * v;
    }
    atomicAdd(&sum[tid], s);
    atomicAdd(&ssq[tid], q);
}

// ---------------- BN finalize: s = gamma*rsqrt(var+eps), t = beta - mu*s ----------------
__global__ void bn_finalize(const float* __restrict__ sum, const float* __restrict__ ssq,
                            const float* __restrict__ gamma, const float* __restrict__ beta,
                            float* __restrict__ s, float* __restrict__ t)
{
    const int j = threadIdx.x;
    const float inv = 1.0f / (float)NBATCH;
    const float mu  = sum[j] * inv;
    float var = ssq[j] * inv - mu * mu;
    var = fmaxf(var, 0.0f);
    const float rs = 1.0f / sqrtf(var + 1e-5f);
    const float sj = gamma[j] * rs;
    s[j] = sj;
    t[j] = fmaf(-mu, sj, beta[j]);
}

// ---------------- middle: relu(bn1(h)) -> log_map0 -> butterfly x3 -> exp_map0 -> ht
//                  + BN2 partial stats (block-reduced, then atomic) ----------------
__global__ __launch_bounds__(256)
void mid_kernel(const float* __restrict__ h, const float* __restrict__ bf,
                const float* __restrict__ s1, const float* __restrict__ t1,
                float* __restrict__ ht, float* __restrict__ sum2, float* __restrict__ ssq2)
{
    __shared__ float bsum[4][256];
    __shared__ float bssq[4][256];
    const int tid  = threadIdx.x;
    const int w    = tid >> 6;
    const int lane = tid & 63;
    const int row0 = blockIdx.x * 64 + w * 16;
    const int c0   = lane * 4;

    // hoisted row-invariant parameters
    const float4 s1v = *reinterpret_cast<const float4*>(&s1[c0]);
    const float4 t1v = *reinterpret_cast<const float4*>(&t1[c0]);
    const float a0 = bf[2 * lane],     a1 = bf[2 * lane + 1];
    const float b0 = bf[128 + 2 * lane], b1 = bf[128 + 2 * lane + 1];
    const float a2 = bf[256 + lane],   b2 = bf[320 + lane];
    const float a3 = bf[384 + (lane >> 1)], b3 = bf[416 + (lane >> 1)];
    const float sgn = (lane & 1) ? -1.0f : 1.0f;
    const float sc  = sqrtf(1e-3f);

    float ps0 = 0, ps1 = 0, ps2 = 0, ps3 = 0;
    float q0 = 0, q1 = 0, q2 = 0, q3 = 0;

    for (int r = 0; r < 16; ++r) {
        const int row = row0 + r;
        const float4 v = *reinterpret_cast<const float4*>(&h[(size_t)row * HIDD + c0]);
        // BN1 + relu
        float x0 = fmaxf(fmaf(v.x, s1v.x, t1v.x), 0.0f);
        float x1 = fmaxf(fmaf(v.y, s1v.y, t1v.y), 0.0f);
        float x2 = fmaxf(fmaf(v.z, s1v.z, t1v.z), 0.0f);
        float x3 = fmaxf(fmaf(v.w, s1v.w, t1v.w), 0.0f);
        // log_map0
        float n2 = x0 * x0 + x1 * x1 + x2 * x2 + x3 * x3;
        n2 = wave_allreduce_sum(n2);
        float sn = sc * sqrtf(n2);
        sn = fminf(fmaxf(sn, 1e-7f), 1.0f - 1e-6f);
        const float ls = atanhf(sn) / sn;
        x0 *= ls; x1 *= ls; x2 *= ls; x3 *= ls;
        // butterfly layer 0 (bs=1): pairs (4L,4L+1) blk=2L ; (4L+2,4L+3) blk=2L+1
        const float y0 = fmaf(a0, x0,  b0 * x1);
        const float y1 = fmaf(a0, x1, -b0 * x0);
        const float y2 = fmaf(a1, x2,  b1 * x3);
        const float y3 = fmaf(a1, x3, -b1 * x2);
        // layer 1 (bs=2): blk=L, x1=(y0,y1), x2=(y2,y3)
        const float z0 = fmaf(a2, y0,  b2 * y2);
        const float z1 = fmaf(a2, y1,  b2 * y3);
        const float z2 = fmaf(a2, y2, -b2 * y0);
        const float z3 = fmaf(a2, y3, -b2 * y1);
        // layer 2 (bs=4): blk=L>>1, even lane holds x1, odd lane holds x2
        const float p0 = __shfl_xor(z0, 1);
        const float p1 = __shfl_xor(z1, 1);
        const float p2 = __shfl_xor(z2, 1);
        const float p3 = __shfl_xor(z3, 1);
        const float w0 = fmaf(a3, z0, sgn * (b3 * p0));
        const float w1 = fmaf(a3, z1, sgn * (b3 * p1));
        const float w2 = fmaf(a3, z2, sgn * (b3 * p2));
        const float w3 = fmaf(a3, z3, sgn * (b3 * p3));
        // exp_map0
        float m2 = w0 * w0 + w1 * w1 + w2 * w2 + w3 * w3;
        m2 = wave_allreduce_sum(m2);
        const float sn2 = fmaxf(sc * sqrtf(m2), 1e-7f);
        const float es = tanhf(sn2) / sn2;
        const float o0 = es * w0, o1 = es * w1, o2 = es * w2, o3 = es * w3;
        *reinterpret_cast<float4*>(&ht[(size_t)row * HIDD + c0]) = make_float4(o0, o1, o2, o3);
        ps0 += o0; ps1 += o1; ps2 += o2; ps3 += o3;
        q0 += o0 * o0; q1 += o1 * o1; q2 += o2 * o2; q3 += o3 * o3;
    }

    bsum[w][c0 + 0] = ps0; bsum[w][c0 + 1] = ps1; bsum[w][c0 + 2] = ps2; bsum[w][c0 + 3] = ps3;
    bssq[w][c0 + 0] = q0;  bssq[w][c0 + 1] = q1;  bssq[w][c0 + 2] = q2;  bssq[w][c0 + 3] = q3;
    __syncthreads();
    if (tid < 256) {
        const float s = bsum[0][tid] + bsum[1][tid] + bsum[2][tid] + bsum[3][tid];
        const float q = bssq[0][tid] + bssq[1][tid] + bssq[2][tid] + bssq[3][tid];
        atomicAdd(&sum2[tid], s);
        atomicAdd(&ssq2[tid], q);
    }
}

extern "C" void kernel_launch(void* const* d_in, const int* in_sizes, int n_in,
                              void* d_out, int out_size, void* d_ws, size_t ws_size,
                              hipStream_t stream)
{
    const float* x   = (const float*)d_in[0];
    const float* w1  = (const float*)d_in[1];
    const float* b1  = (const float*)d_in[2];
    const float* g1  = (const float*)d_in[3];
    const float* be1 = (const float*)d_in[4];
    const float* bf  = (const float*)d_in[5];
    const float* g2  = (const float*)d_in[6];
    const float* be2 = (const float*)d_in[7];
    const float* w2  = (const float*)d_in[8];
    const float* b2  = (const float*)d_in[9];

    float* out = (float*)d_out;
    float* ws  = (float*)d_ws;

    float* ht   = ws;                                   // 32768*256 floats
    float* stat = ws + (size_t)NBATCH * HIDD;           // stats region
    float* sum1 = stat +    0;
    float* ssq1 = stat +  256;
    float* sum2 = stat +  512;
    float* ssq2 = stat +  768;
    float* s1   = stat + 1024;
    float* t1   = stat + 1280;
    float* s2   = stat + 1536;
    float* t2   = stat + 1792;

    float* h = out;  // park h[32768][256] in d_out; dead before GEMM2 overwrites

    hipMemsetAsync(stat, 0, 1024 * sizeof(float), stream);

    // GEMM1: h = x @ fc1_w^T + fc1_b     (M=32768, N=256, K=784)
    gemm_tn<false, false><<<256 * 2, 256, 0, stream>>>(x, w1, b1, nullptr, nullptr,
                                                       h, NBATCH, HIDD, IND, 2);
    // BN1 statistics
    bn_stats<<<NBATCH / 128, 256, 0, stream>>>(h, sum1, ssq1);
    bn_finalize<<<1, 256, 0, stream>>>(sum1, ssq1, g1, be1, s1, t1);
    // middle: bn1+relu, log-map, butterfly x3, exp-map, BN2 stats
    mid_kernel<<<512, 256, 0, stream>>>(h, bf, s1, t1, ht, sum2, ssq2);
    bn_finalize<<<1, 256, 0, stream>>>(sum2, ssq2, g2, be2, s2, t2);
    // GEMM2: out = relu(bn2(ht)) @ fc2_w^T + fc2_b   (M=32768, N=1000, K=256)
    gemm_tn<true, true><<<256 * 8, 256, 0, stream>>>(ht, w2, b2, s2, t2,
                                                     out, NBATCH, OUTD, HIDD, 8);
}

// Round 2
// 181.294 us; speedup vs baseline: 2.4806x; 2.4806x over previous
//
#include <hip/hip_runtime.h>
#include <math.h>

#define NBATCH 32768
#define IND    784
#define HIDD   256
#define OUTD   1000

typedef _Float16 half8 __attribute__((ext_vector_type(8)));
typedef float    floatx4 __attribute__((ext_vector_type(4)));

__device__ __forceinline__ float wave_allreduce_sum(float v) {
    #pragma unroll
    for (int off = 32; off >= 1; off >>= 1) v += __shfl_xor(v, off);
    return v;
}

// ================= MFMA GEMM: C[M,N] = op(A)[M,K] @ Bw[N,K]^T * invScale + bias =================
// op(A) = FUSE ? relu(sA[k]*A + tA[k]) : A      (sA/tA pre-scaled by 1024 on host-side finalize)
// STATS: also atomically accumulate per-column sum/sumsq of the STORED C values (for BN1).
template<bool FUSE, bool NCHK, bool STATS>
__global__ __launch_bounds__(256, 2)
void gemm_mfma(const float* __restrict__ A, const float* __restrict__ Bw,
               const float* __restrict__ bias,
               const float* __restrict__ sA, const float* __restrict__ tA,
               float* __restrict__ C, float* __restrict__ sumO, float* __restrict__ ssqO,
               int M, int N, int K, int nbn, float invScale)
{
    __shared__ __align__(16) _Float16 As[128][40];   // 32 k + 8 pad (80B row, conflict-free b128)
    __shared__ __align__(16) _Float16 Bs[128][40];
    __shared__ float ssv[256], ttv[256];             // FUSE only
    __shared__ float redS[2][128], redQ[2][128];     // STATS only

    const int tid = threadIdx.x;
    const int bid = blockIdx.x;
    const int bm = bid / nbn, bn = bid % nbn;
    const int m0 = bm * 128, n0 = bn * 128;

    if (FUSE) {
        for (int i = tid; i < K; i += 256) { ssv[i] = sA[i]; ttv[i] = tA[i]; }
        __syncthreads();
    }

    floatx4 acc[4][4];
    #pragma unroll
    for (int i = 0; i < 4; ++i)
        #pragma unroll
        for (int j = 0; j < 4; ++j) acc[i][j] = (floatx4){0.f, 0.f, 0.f, 0.f};

    const int row  = tid >> 1;      // staging: 0..127
    const int kh   = tid & 1;       // staging: which 16-col half
    const int lane = tid & 63;
    const int wv   = tid >> 6;
    const int wr   = wv >> 1, wc = wv & 1;
    const int l15  = lane & 15, lg = lane >> 4;

    for (int k0 = 0; k0 < K; k0 += 32) {
        const int  kb   = k0 + kh * 16;
        const bool kval = kb < K;              // K is a multiple of 16

        // ---- stage A (with optional fused BN2+relu) ----
        {
            float av[16];
            if (kval) {
                const float* src = &A[(size_t)(m0 + row) * K + kb];
                #pragma unroll
                for (int c = 0; c < 4; ++c) {
                    float4 v = *reinterpret_cast<const float4*>(src + c * 4);
                    av[c*4+0] = v.x; av[c*4+1] = v.y; av[c*4+2] = v.z; av[c*4+3] = v.w;
                }
                if (FUSE) {
                    #pragma unroll
                    for (int j = 0; j < 16; ++j)
                        av[j] = fmaxf(fmaf(av[j], ssv[kb + j], ttv[kb + j]), 0.0f);
                }
            } else {
                #pragma unroll
                for (int j = 0; j < 16; ++j) av[j] = 0.0f;
            }
            half8 h0, h1;
            #pragma unroll
            for (int j = 0; j < 8; ++j) { h0[j] = (_Float16)av[j]; h1[j] = (_Float16)av[8 + j]; }
            *reinterpret_cast<half8*>(&As[row][kh * 16])     = h0;
            *reinterpret_cast<half8*>(&As[row][kh * 16 + 8]) = h1;
        }
        // ---- stage B ----
        {
            float bv[16];
            const bool nval = !NCHK || (n0 + row) < N;
            if (kval && nval) {
                const float* src = &Bw[(size_t)(n0 + row) * K + kb];
                #pragma unroll
                for (int c = 0; c < 4; ++c) {
                    float4 v = *reinterpret_cast<const float4*>(src + c * 4);
                    bv[c*4+0] = v.x; bv[c*4+1] = v.y; bv[c*4+2] = v.z; bv[c*4+3] = v.w;
                }
            } else {
                #pragma unroll
                for (int j = 0; j < 16; ++j) bv[j] = 0.0f;
            }
            half8 h0, h1;
            #pragma unroll
            for (int j = 0; j < 8; ++j) { h0[j] = (_Float16)bv[j]; h1[j] = (_Float16)bv[8 + j]; }
            *reinterpret_cast<half8*>(&Bs[row][kh * 16])     = h0;
            *reinterpret_cast<half8*>(&Bs[row][kh * 16 + 8]) = h1;
        }
        __syncthreads();

        half8 af[4], bfr[4];
        #pragma unroll
        for (int i = 0; i < 4; ++i)
            af[i] = *reinterpret_cast<const half8*>(&As[wr * 64 + i * 16 + l15][lg * 8]);
        #pragma unroll
        for (int j = 0; j < 4; ++j)
            bfr[j] = *reinterpret_cast<const half8*>(&Bs[wc * 64 + j * 16 + l15][lg * 8]);
        #pragma unroll
        for (int i = 0; i < 4; ++i)
            #pragma unroll
            for (int j = 0; j < 4; ++j)
                acc[i][j] = __builtin_amdgcn_mfma_f32_16x16x32_f16(af[i], bfr[j], acc[i][j], 0, 0, 0);
        __syncthreads();
    }

    // ---- epilogue: scale + bias, store, optional column stats ----
    float bv4[4]; int col4[4];
    #pragma unroll
    for (int j = 0; j < 4; ++j) {
        col4[j] = n0 + wc * 64 + j * 16 + l15;
        bv4[j] = (!NCHK || col4[j] < N) ? bias[col4[j]] : 0.0f;
    }
    float sJ[4], qJ[4];
    #pragma unroll
    for (int j = 0; j < 4; ++j) {
        float s = 0.f, q = 0.f;
        const bool cok = !NCHK || col4[j] < N;
        #pragma unroll
        for (int i = 0; i < 4; ++i) {
            const int r0 = m0 + wr * 64 + i * 16 + lg * 4;
            #pragma unroll
            for (int r = 0; r < 4; ++r) {
                const float v = fmaf(acc[i][j][r], invScale, bv4[j]);
                if (cok) C[(size_t)(r0 + r) * N + col4[j]] = v;
                s += v; q += v * v;
            }
        }
        sJ[j] = s; qJ[j] = q;
    }
    if (STATS) {
        #pragma unroll
        for (int j = 0; j < 4; ++j) {
            float s = sJ[j], q = qJ[j];
            s += __shfl_xor(s, 16); s += __shfl_xor(s, 32);
            q += __shfl_xor(q, 16); q += __shfl_xor(q, 32);
            if (lg == 0) {
                redS[wr][wc * 64 + j * 16 + l15] = s;
                redQ[wr][wc * 64 + j * 16 + l15] = q;
            }
        }
        __syncthreads();
        if (tid < 128) {
            atomicAdd(&sumO[n0 + tid], redS[0][tid] + redS[1][tid]);
            atomicAdd(&ssqO[n0 + tid], redQ[0][tid] + redQ[1][tid]);
        }
    }
}

// ---------------- BN finalize: s = gamma*rsqrt(var+eps)*outScale, t = (beta - mu*s̃)*outScale ----
__global__ void bn_finalize(const float* __restrict__ sum, const float* __restrict__ ssq,
                            const float* __restrict__ gamma, const float* __restrict__ beta,
                            float* __restrict__ s, float* __restrict__ t, float outScale)
{
    const int j = threadIdx.x;
    const float inv = 1.0f / (float)NBATCH;
    const float mu  = sum[j] * inv;
    float var = ssq[j] * inv - mu * mu;
    var = fmaxf(var, 0.0f);
    const float rs = 1.0f / sqrtf(var + 1e-5f);
    const float sj = gamma[j] * rs;
    s[j] = sj * outScale;
    t[j] = fmaf(-mu, sj, beta[j]) * outScale;
}

// ---------------- middle: relu(bn1(h)) -> log_map0 -> butterfly x3 -> exp_map0 -> ht
//                  + BN2 partial stats ----------------
__global__ __launch_bounds__(256)
void mid_kernel(const float* __restrict__ h, const float* __restrict__ bf,
                const float* __restrict__ s1, const float* __restrict__ t1,
                float* __restrict__ ht, float* __restrict__ sum2, float* __restrict__ ssq2)
{
    __shared__ float bsum[4][256];
    __shared__ float bssq[4][256];
    const int tid  = threadIdx.x;
    const int w    = tid >> 6;
    const int lane = tid & 63;
    const int row0 = blockIdx.x * 64 + w * 16;
    const int c0   = lane * 4;

    const float4 s1v = *reinterpret_cast<const float4*>(&s1[c0]);
    const float4 t1v = *reinterpret_cast<const float4*>(&t1[c0]);
    const float a0 = bf[2 * lane],       a1 = bf[2 * lane + 1];
    const float b0 = bf[128 + 2 * lane], b1 = bf[128 + 2 * lane + 1];
    const float a2 = bf[256 + lane],     b2 = bf[320 + lane];
    const float a3 = bf[384 + (lane >> 1)], b3 = bf[416 + (lane >> 1)];
    const float sgn = (lane & 1) ? -1.0f : 1.0f;
    const float sc  = sqrtf(1e-3f);

    float ps0 = 0, ps1 = 0, ps2 = 0, ps3 = 0;
    float q0 = 0, q1 = 0, q2 = 0, q3 = 0;

    for (int r = 0; r < 16; ++r) {
        const int row = row0 + r;
        const float4 v = *reinterpret_cast<const float4*>(&h[(size_t)row * HIDD + c0]);
        float x0 = fmaxf(fmaf(v.x, s1v.x, t1v.x), 0.0f);
        float x1 = fmaxf(fmaf(v.y, s1v.y, t1v.y), 0.0f);
        float x2 = fmaxf(fmaf(v.z, s1v.z, t1v.z), 0.0f);
        float x3 = fmaxf(fmaf(v.w, s1v.w, t1v.w), 0.0f);
        float n2 = x0 * x0 + x1 * x1 + x2 * x2 + x3 * x3;
        n2 = wave_allreduce_sum(n2);
        float sn = sc * sqrtf(n2);
        sn = fminf(fmaxf(sn, 1e-7f), 1.0f - 1e-6f);
        const float ls = atanhf(sn) / sn;
        x0 *= ls; x1 *= ls; x2 *= ls; x3 *= ls;
        const float y0 = fmaf(a0, x0,  b0 * x1);
        const float y1 = fmaf(a0, x1, -b0 * x0);
        const float y2 = fmaf(a1, x2,  b1 * x3);
        const float y3 = fmaf(a1, x3, -b1 * x2);
        const float z0 = fmaf(a2, y0,  b2 * y2);
        const float z1 = fmaf(a2, y1,  b2 * y3);
        const float z2 = fmaf(a2, y2, -b2 * y0);
        const float z3 = fmaf(a2, y3, -b2 * y1);
        const float p0 = __shfl_xor(z0, 1);
        const float p1 = __shfl_xor(z1, 1);
        const float p2 = __shfl_xor(z2, 1);
        const float p3 = __shfl_xor(z3, 1);
        const float w0 = fmaf(a3, z0, sgn * (b3 * p0));
        const float w1 = fmaf(a3, z1, sgn * (b3 * p1));
        const float w2 = fmaf(a3, z2, sgn * (b3 * p2));
        const float w3 = fmaf(a3, z3, sgn * (b3 * p3));
        float m2 = w0 * w0 + w1 * w1 + w2 * w2 + w3 * w3;
        m2 = wave_allreduce_sum(m2);
        const float sn2 = fmaxf(sc * sqrtf(m2), 1e-7f);
        const float es = tanhf(sn2) / sn2;
        const float o0 = es * w0, o1 = es * w1, o2 = es * w2, o3 = es * w3;
        *reinterpret_cast<float4*>(&ht[(size_t)row * HIDD + c0]) = make_float4(o0, o1, o2, o3);
        ps0 += o0; ps1 += o1; ps2 += o2; ps3 += o3;
        q0 += o0 * o0; q1 += o1 * o1; q2 += o2 * o2; q3 += o3 * o3;
    }

    bsum[w][c0 + 0] = ps0; bsum[w][c0 + 1] = ps1; bsum[w][c0 + 2] = ps2; bsum[w][c0 + 3] = ps3;
    bssq[w][c0 + 0] = q0;  bssq[w][c0 + 1] = q1;  bssq[w][c0 + 2] = q2;  bssq[w][c0 + 3] = q3;
    __syncthreads();
    if (tid < 256) {
        const float s = bsum[0][tid] + bsum[1][tid] + bsum[2][tid] + bsum[3][tid];
        const float q = bssq[0][tid] + bssq[1][tid] + bssq[2][tid] + bssq[3][tid];
        atomicAdd(&sum2[tid], s);
        atomicAdd(&ssq2[tid], q);
    }
}

extern "C" void kernel_launch(void* const* d_in, const int* in_sizes, int n_in,
                              void* d_out, int out_size, void* d_ws, size_t ws_size,
                              hipStream_t stream)
{
    const float* x   = (const float*)d_in[0];
    const float* w1  = (const float*)d_in[1];
    const float* b1  = (const float*)d_in[2];
    const float* g1  = (const float*)d_in[3];
    const float* be1 = (const float*)d_in[4];
    const float* bf  = (const float*)d_in[5];
    const float* g2  = (const float*)d_in[6];
    const float* be2 = (const float*)d_in[7];
    const float* w2  = (const float*)d_in[8];
    const float* b2  = (const float*)d_in[9];

    float* out = (float*)d_out;
    float* ws  = (float*)d_ws;

    float* ht   = ws;                                   // 32768*256 floats
    float* stat = ws + (size_t)NBATCH * HIDD;
    float* sum1 = stat +    0;
    float* ssq1 = stat +  256;
    float* sum2 = stat +  512;
    float* ssq2 = stat +  768;
    float* s1   = stat + 1024;
    float* t1   = stat + 1280;
    float* s2   = stat + 1536;
    float* t2   = stat + 1792;

    float* h = out;   // park h[32768][256] in d_out; dead before GEMM2 overwrites

    hipMemsetAsync(stat, 0, 1024 * sizeof(float), stream);

    // GEMM1: h = x @ fc1_w^T + fc1_b  (M=32768,N=256,K=784), fused BN1 column stats
    gemm_mfma<false, false, true><<<512, 256, 0, stream>>>(
        x, w1, b1, nullptr, nullptr, h, sum1, ssq1, NBATCH, HIDD, IND, 2, 1.0f);
    bn_finalize<<<1, 256, 0, stream>>>(sum1, ssq1, g1, be1, s1, t1, 1.0f);
    // middle: bn1+relu, log-map, butterfly x3, exp-map, BN2 stats
    mid_kernel<<<512, 256, 0, stream>>>(h, bf, s1, t1, ht, sum2, ssq2);
    // scale BN2 output by 1024 (keeps GEMM2's fp16 A-operand out of subnormals)
    bn_finalize<<<1, 256, 0, stream>>>(sum2, ssq2, g2, be2, s2, t2, 1024.0f);
    // GEMM2: out = relu(bn2(ht)) @ fc2_w^T + fc2_b  (M=32768,N=1000,K=256), un-scale in epilogue
    gemm_mfma<true, true, false><<<2048, 256, 0, stream>>>(
        ht, w2, b2, s2, t2, out, nullptr, nullptr, NBATCH, OUTD, HIDD, 8, 1.0f / 1024.0f);
}

// Round 3
// 170.388 us; speedup vs baseline: 2.6394x; 1.0640x over previous
//
#include <hip/hip_runtime.h>
#include <math.h>

#define NBATCH 32768
#define IND    784
#define HIDD   256
#define OUTD   1000

typedef _Float16 half8 __attribute__((ext_vector_type(8)));
typedef float    floatx4 __attribute__((ext_vector_type(4)));

__device__ __forceinline__ float wave_allreduce_sum(float v) {
    #pragma unroll
    for (int off = 32; off >= 1; off >>= 1) v += __shfl_xor(v, off);
    return v;
}

// ================= Pipelined MFMA GEMM: C[M,N] = op(A)[M,K] @ Bw[N,K]^T * invScale + bias ======
// op(A) = FUSE ? relu(sA[k]*A + tA[k]) : A      (sA/tA pre-scaled by 1024 in bn_finalize)
// STATS: atomically accumulate per-column sum/sumsq of stored C (for BN1).
// K-loop: double-buffered LDS + register prefetch (tile t computes, t+1 converts, t+2 loads).
template<bool FUSE, bool NCHK, bool STATS>
__global__ __launch_bounds__(256, 2)
void gemm_mfma(const float* __restrict__ A, const float* __restrict__ Bw,
               const float* __restrict__ bias,
               const float* __restrict__ sA, const float* __restrict__ tA,
               float* __restrict__ C, float* __restrict__ sumO, float* __restrict__ ssqO,
               int M, int N, int K, int nbn, float invScale)
{
    __shared__ __align__(16) _Float16 As[2][128][40];   // 32 k + 8 pad (80B row, b128-conflict-free)
    __shared__ __align__(16) _Float16 Bs[2][128][40];
    __shared__ float ssv[256], ttv[256];                // FUSE only
    __shared__ float redS[2][128], redQ[2][128];        // STATS only

    const int tid = threadIdx.x;
    const int bid = blockIdx.x;
    const int bm = bid / nbn, bn = bid % nbn;
    const int m0 = bm * 128, n0 = bn * 128;

    const int row  = tid >> 1;      // staging row 0..127
    const int kh   = tid & 1;       // which 16-wide k-half
    const int lane = tid & 63;
    const int wv   = tid >> 6;
    const int wr   = wv >> 1, wc = wv & 1;
    const int l15  = lane & 15, lg = lane >> 4;

    const int nt = (K + 31) >> 5;

    if (FUSE) {
        for (int i = tid; i < K; i += 256) { ssv[i] = sA[i]; ttv[i] = tA[i]; }
        __syncthreads();
    }

    floatx4 acc[4][4];
    #pragma unroll
    for (int i = 0; i < 4; ++i)
        #pragma unroll
        for (int j = 0; j < 4; ++j) acc[i][j] = (floatx4){0.f, 0.f, 0.f, 0.f};

    float ra[16], rb[16];

    auto load_tile = [&](int t) {
        const int kb = t * 32 + kh * 16;        // K is a multiple of 16
        if (kb < K) {
            const float* srcA = &A[(size_t)(m0 + row) * K + kb];
            #pragma unroll
            for (int c = 0; c < 4; ++c) {
                float4 v = *reinterpret_cast<const float4*>(srcA + c * 4);
                ra[c*4+0] = v.x; ra[c*4+1] = v.y; ra[c*4+2] = v.z; ra[c*4+3] = v.w;
            }
            if (!NCHK || (n0 + row) < N) {
                const float* srcB = &Bw[(size_t)(n0 + row) * K + kb];
                #pragma unroll
                for (int c = 0; c < 4; ++c) {
                    float4 v = *reinterpret_cast<const float4*>(srcB + c * 4);
                    rb[c*4+0] = v.x; rb[c*4+1] = v.y; rb[c*4+2] = v.z; rb[c*4+3] = v.w;
                }
            } else {
                #pragma unroll
                for (int j = 0; j < 16; ++j) rb[j] = 0.0f;
            }
        } else {
            #pragma unroll
            for (int j = 0; j < 16; ++j) { ra[j] = 0.0f; rb[j] = 0.0f; }
        }
    };

    auto store_tile = [&](int buf, int t) {
        const int kb = t * 32 + kh * 16;
        float av[16];
        #pragma unroll
        for (int j = 0; j < 16; ++j) av[j] = ra[j];
        if (FUSE && kb < K) {
            #pragma unroll
            for (int j = 0; j < 16; ++j)
                av[j] = fmaxf(fmaf(av[j], ssv[kb + j], ttv[kb + j]), 0.0f);
        }
        half8 h0, h1;
        #pragma unroll
        for (int j = 0; j < 8; ++j) { h0[j] = (_Float16)av[j]; h1[j] = (_Float16)av[8 + j]; }
        *reinterpret_cast<half8*>(&As[buf][row][kh * 16])     = h0;
        *reinterpret_cast<half8*>(&As[buf][row][kh * 16 + 8]) = h1;
        #pragma unroll
        for (int j = 0; j < 8; ++j) { h0[j] = (_Float16)rb[j]; h1[j] = (_Float16)rb[8 + j]; }
        *reinterpret_cast<half8*>(&Bs[buf][row][kh * 16])     = h0;
        *reinterpret_cast<half8*>(&Bs[buf][row][kh * 16 + 8]) = h1;
    };

    // prologue: tile0 -> LDS[0]; tile1 in regs
    load_tile(0);
    store_tile(0, 0);
    load_tile(1);
    __syncthreads();

    int cur = 0;
    for (int t = 0; t < nt; ++t) {
        half8 af[4], bfr[4];
        #pragma unroll
        for (int i = 0; i < 4; ++i)
            af[i] = *reinterpret_cast<const half8*>(&As[cur][wr * 64 + i * 16 + l15][lg * 8]);
        #pragma unroll
        for (int j = 0; j < 4; ++j)
            bfr[j] = *reinterpret_cast<const half8*>(&Bs[cur][wc * 64 + j * 16 + l15][lg * 8]);
        #pragma unroll
        for (int i = 0; i < 4; ++i)
            #pragma unroll
            for (int j = 0; j < 4; ++j)
                acc[i][j] = __builtin_amdgcn_mfma_f32_16x16x32_f16(af[i], bfr[j], acc[i][j], 0, 0, 0);
        if (t + 1 < nt) {
            store_tile(cur ^ 1, t + 1);   // vmcnt-waits on regs(t+1), convert, ds_write
            load_tile(t + 2);             // issue next loads (predicated; zeros if past K)
        }
        __syncthreads();
        cur ^= 1;
    }

    // ---- epilogue: scale + bias, store, optional column stats ----
    float bv4[4]; int col4[4];
    #pragma unroll
    for (int j = 0; j < 4; ++j) {
        col4[j] = n0 + wc * 64 + j * 16 + l15;
        bv4[j] = (!NCHK || col4[j] < N) ? bias[col4[j]] : 0.0f;
    }
    float sJ[4], qJ[4];
    #pragma unroll
    for (int j = 0; j < 4; ++j) {
        float s = 0.f, q = 0.f;
        const bool cok = !NCHK || col4[j] < N;
        #pragma unroll
        for (int i = 0; i < 4; ++i) {
            const int r0 = m0 + wr * 64 + i * 16 + lg * 4;
            #pragma unroll
            for (int r = 0; r < 4; ++r) {
                const float v = fmaf(acc[i][j][r], invScale, bv4[j]);
                if (cok) C[(size_t)(r0 + r) * N + col4[j]] = v;
                s += v; q += v * v;
            }
        }
        sJ[j] = s; qJ[j] = q;
    }
    if (STATS) {
        #pragma unroll
        for (int j = 0; j < 4; ++j) {
            float s = sJ[j], q = qJ[j];
            s += __shfl_xor(s, 16); s += __shfl_xor(s, 32);
            q += __shfl_xor(q, 16); q += __shfl_xor(q, 32);
            if (lg == 0) {
                redS[wr][wc * 64 + j * 16 + l15] = s;
                redQ[wr][wc * 64 + j * 16 + l15] = q;
            }
        }
        __syncthreads();
        if (tid < 128) {
            atomicAdd(&sumO[n0 + tid], redS[0][tid] + redS[1][tid]);
            atomicAdd(&ssqO[n0 + tid], redQ[0][tid] + redQ[1][tid]);
        }
    }
}

// ---------------- BN finalize: s = gamma*rsqrt(var+eps)*outScale, t = (beta - mu*s̃)*outScale ----
__global__ void bn_finalize(const float* __restrict__ sum, const float* __restrict__ ssq,
                            const float* __restrict__ gamma, const float* __restrict__ beta,
                            float* __restrict__ s, float* __restrict__ t, float outScale)
{
    const int j = threadIdx.x;
    const float inv = 1.0f / (float)NBATCH;
    const float mu  = sum[j] * inv;
    float var = ssq[j] * inv - mu * mu;
    var = fmaxf(var, 0.0f);
    const float rs = 1.0f / sqrtf(var + 1e-5f);
    const float sj = gamma[j] * rs;
    s[j] = sj * outScale;
    t[j] = fmaf(-mu, sj, beta[j]) * outScale;
}

// ---------------- middle: relu(bn1(h)) -> log_map0 -> butterfly x3 -> exp_map0 -> ht
//                  + BN2 partial stats ----------------
__global__ __launch_bounds__(256)
void mid_kernel(const float* __restrict__ h, const float* __restrict__ bf,
                const float* __restrict__ s1, const float* __restrict__ t1,
                float* __restrict__ ht, float* __restrict__ sum2, float* __restrict__ ssq2)
{
    __shared__ float bsum[4][256];
    __shared__ float bssq[4][256];
    const int tid  = threadIdx.x;
    const int w    = tid >> 6;
    const int lane = tid & 63;
    const int row0 = blockIdx.x * 64 + w * 16;
    const int c0   = lane * 4;

    const float4 s1v = *reinterpret_cast<const float4*>(&s1[c0]);
    const float4 t1v = *reinterpret_cast<const float4*>(&t1[c0]);
    const float a0 = bf[2 * lane],       a1 = bf[2 * lane + 1];
    const float b0 = bf[128 + 2 * lane], b1 = bf[128 + 2 * lane + 1];
    const float a2 = bf[256 + lane],     b2 = bf[320 + lane];
    const float a3 = bf[384 + (lane >> 1)], b3 = bf[416 + (lane >> 1)];
    const float sgn = (lane & 1) ? -1.0f : 1.0f;
    const float sc  = sqrtf(1e-3f);

    float ps0 = 0, ps1 = 0, ps2 = 0, ps3 = 0;
    float q0 = 0, q1 = 0, q2 = 0, q3 = 0;

    for (int r = 0; r < 16; ++r) {
        const int row = row0 + r;
        const float4 v = *reinterpret_cast<const float4*>(&h[(size_t)row * HIDD + c0]);
        float x0 = fmaxf(fmaf(v.x, s1v.x, t1v.x), 0.0f);
        float x1 = fmaxf(fmaf(v.y, s1v.y, t1v.y), 0.0f);
        float x2 = fmaxf(fmaf(v.z, s1v.z, t1v.z), 0.0f);
        float x3 = fmaxf(fmaf(v.w, s1v.w, t1v.w), 0.0f);
        float n2 = x0 * x0 + x1 * x1 + x2 * x2 + x3 * x3;
        n2 = wave_allreduce_sum(n2);
        float sn = sc * sqrtf(n2);
        sn = fminf(fmaxf(sn, 1e-7f), 1.0f - 1e-6f);
        const float ls = atanhf(sn) / sn;
        x0 *= ls; x1 *= ls; x2 *= ls; x3 *= ls;
        const float y0 = fmaf(a0, x0,  b0 * x1);
        const float y1 = fmaf(a0, x1, -b0 * x0);
        const float y2 = fmaf(a1, x2,  b1 * x3);
        const float y3 = fmaf(a1, x3, -b1 * x2);
        const float z0 = fmaf(a2, y0,  b2 * y2);
        const float z1 = fmaf(a2, y1,  b2 * y3);
        const float z2 = fmaf(a2, y2, -b2 * y0);
        const float z3 = fmaf(a2, y3, -b2 * y1);
        const float p0 = __shfl_xor(z0, 1);
        const float p1 = __shfl_xor(z1, 1);
        const float p2 = __shfl_xor(z2, 1);
        const float p3 = __shfl_xor(z3, 1);
        const float w0 = fmaf(a3, z0, sgn * (b3 * p0));
        const float w1 = fmaf(a3, z1, sgn * (b3 * p1));
        const float w2 = fmaf(a3, z2, sgn * (b3 * p2));
        const float w3 = fmaf(a3, z3, sgn * (b3 * p3));
        float m2 = w0 * w0 + w1 * w1 + w2 * w2 + w3 * w3;
        m2 = wave_allreduce_sum(m2);
        const float sn2 = fmaxf(sc * sqrtf(m2), 1e-7f);
        const float es = tanhf(sn2) / sn2;
        const float o0 = es * w0, o1 = es * w1, o2 = es * w2, o3 = es * w3;
        *reinterpret_cast<float4*>(&ht[(size_t)row * HIDD + c0]) = make_float4(o0, o1, o2, o3);
        ps0 += o0; ps1 += o1; ps2 += o2; ps3 += o3;
        q0 += o0 * o0; q1 += o1 * o1; q2 += o2 * o2; q3 += o3 * o3;
    }

    bsum[w][c0 + 0] = ps0; bsum[w][c0 + 1] = ps1; bsum[w][c0 + 2] = ps2; bsum[w][c0 + 3] = ps3;
    bssq[w][c0 + 0] = q0;  bssq[w][c0 + 1] = q1;  bssq[w][c0 + 2] = q2;  bssq[w][c0 + 3] = q3;
    __syncthreads();
    if (tid < 256) {
        const float s = bsum[0][tid] + bsum[1][tid] + bsum[2][tid] + bsum[3][tid];
        const float q = bssq[0][tid] + bssq[1][tid] + bssq[2][tid] + bssq[3][tid];
        atomicAdd(&sum2[tid], s);
        atomicAdd(&ssq2[tid], q);
    }
}

extern "C" void kernel_launch(void* const* d_in, const int* in_sizes, int n_in,
                              void* d_out, int out_size, void* d_ws, size_t ws_size,
                              hipStream_t stream)
{
    const float* x   = (const float*)d_in[0];
    const float* w1  = (const float*)d_in[1];
    const float* b1  = (const float*)d_in[2];
    const float* g1  = (const float*)d_in[3];
    const float* be1 = (const float*)d_in[4];
    const float* bf  = (const float*)d_in[5];
    const float* g2  = (const float*)d_in[6];
    const float* be2 = (const float*)d_in[7];
    const float* w2  = (const float*)d_in[8];
    const float* b2  = (const float*)d_in[9];

    float* out = (float*)d_out;
    float* ws  = (float*)d_ws;

    float* ht   = ws;                                   // 32768*256 floats
    float* stat = ws + (size_t)NBATCH * HIDD;
    float* sum1 = stat +    0;
    float* ssq1 = stat +  256;
    float* sum2 = stat +  512;
    float* ssq2 = stat +  768;
    float* s1   = stat + 1024;
    float* t1   = stat + 1280;
    float* s2   = stat + 1536;
    float* t2   = stat + 1792;

    float* h = out;   // park h[32768][256] in d_out; dead before GEMM2 overwrites

    hipMemsetAsync(stat, 0, 1024 * sizeof(float), stream);

    // GEMM1: h = x @ fc1_w^T + fc1_b  (M=32768,N=256,K=784), fused BN1 column stats
    gemm_mfma<false, false, true><<<512, 256, 0, stream>>>(
        x, w1, b1, nullptr, nullptr, h, sum1, ssq1, NBATCH, HIDD, IND, 2, 1.0f);
    bn_finalize<<<1, 256, 0, stream>>>(sum1, ssq1, g1, be1, s1, t1, 1.0f);
    // middle: bn1+relu, log-map, butterfly x3, exp-map, BN2 stats
    mid_kernel<<<512, 256, 0, stream>>>(h, bf, s1, t1, ht, sum2, ssq2);
    // scale BN2 output by 1024 (keeps GEMM2's fp16 A-operand out of subnormals)
    bn_finalize<<<1, 256, 0, stream>>>(sum2, ssq2, g2, be2, s2, t2, 1024.0f);
    // GEMM2: out = relu(bn2(ht)) @ fc2_w^T + fc2_b  (M=32768,N=1000,K=256), un-scale in epilogue
    gemm_mfma<true, true, false><<<2048, 256, 0, stream>>>(
        ht, w2, b2, s2, t2, out, nullptr, nullptr, NBATCH, OUTD, HIDD, 8, 1.0f / 1024.0f);
}

// Round 4
// 166.889 us; speedup vs baseline: 2.6948x; 1.0210x over previous
//
#include <hip/hip_runtime.h>
#include <math.h>

#define NBATCH 32768
#define IND    784
#define HIDD   256
#define OUTD   1000

typedef _Float16 half8 __attribute__((ext_vector_type(8)));
typedef float    floatx4 __attribute__((ext_vector_type(4)));

__device__ __forceinline__ float wave_allreduce_sum(float v) {
    #pragma unroll
    for (int off = 32; off >= 1; off >>= 1) v += __shfl_xor(v, off);
    return v;
}

// ================= Pipelined MFMA GEMM: C[M,N] = op(A)[M,K] @ Bw[N,K]^T * invScale + bias ======
// op(A) = FUSE ? relu(sA[k]*A + tA[k]) : A      (sA/tA pre-scaled by 1024 in bn_finalize)
// STATS: atomically accumulate per-column sum/sumsq of stored C (for BN1).
// K-loop: double-buffered LDS + register prefetch. MFMA operands SWAPPED (D = B_frag * A_frag)
// so each lane's 4 acc regs are 4 consecutive n -> float4 coalesced C stores.
// Grid: XCD-chunked swizzle so all n-blocks of an A-panel share one XCD's L2.
template<bool FUSE, bool NCHK, bool STATS>
__global__ __launch_bounds__(256, 3)
void gemm_mfma(const float* __restrict__ A, const float* __restrict__ Bw,
               const float* __restrict__ bias,
               const float* __restrict__ sA, const float* __restrict__ tA,
               float* __restrict__ C, float* __restrict__ sumO, float* __restrict__ ssqO,
               int M, int N, int K, int nbn, float invScale)
{
    __shared__ __align__(16) _Float16 As[2][128][40];   // 80B row: all-phase bank-uniform for b128
    __shared__ __align__(16) _Float16 Bs[2][128][40];
    __shared__ float ssv[FUSE ? 256 : 1], ttv[FUSE ? 256 : 1];
    __shared__ float redS[2][STATS ? 128 : 1], redQ[2][STATS ? 128 : 1];

    const int tid = threadIdx.x;
    // XCD-chunked swizzle (grid divisible by 8): co-locate same-bm blocks on one XCD
    const int bid0 = blockIdx.x;
    const int vbid = (bid0 & 7) * ((int)gridDim.x >> 3) + (bid0 >> 3);
    const int bm = vbid / nbn, bn = vbid % nbn;
    const int m0 = bm * 128, n0 = bn * 128;

    const int row  = tid >> 1;      // staging row 0..127
    const int kh   = tid & 1;       // which 16-wide k-half
    const int lane = tid & 63;
    const int wv   = tid >> 6;
    const int wr   = wv >> 1, wc = wv & 1;
    const int l15  = lane & 15, lg = lane >> 4;

    const int nt = (K + 31) >> 5;

    if (FUSE) {
        for (int i = tid; i < K; i += 256) { ssv[i] = sA[i]; ttv[i] = tA[i]; }
        __syncthreads();
    }

    floatx4 acc[4][4];
    #pragma unroll
    for (int i = 0; i < 4; ++i)
        #pragma unroll
        for (int j = 0; j < 4; ++j) acc[i][j] = (floatx4){0.f, 0.f, 0.f, 0.f};

    float ra[16], rb[16];

    auto load_tile = [&](int t) {
        const int kb = t * 32 + kh * 16;        // K is a multiple of 16
        if (kb < K) {
            const float* srcA = &A[(size_t)(m0 + row) * K + kb];
            #pragma unroll
            for (int c = 0; c < 4; ++c) {
                float4 v = *reinterpret_cast<const float4*>(srcA + c * 4);
                ra[c*4+0] = v.x; ra[c*4+1] = v.y; ra[c*4+2] = v.z; ra[c*4+3] = v.w;
            }
            if (!NCHK || (n0 + row) < N) {
                const float* srcB = &Bw[(size_t)(n0 + row) * K + kb];
                #pragma unroll
                for (int c = 0; c < 4; ++c) {
                    float4 v = *reinterpret_cast<const float4*>(srcB + c * 4);
                    rb[c*4+0] = v.x; rb[c*4+1] = v.y; rb[c*4+2] = v.z; rb[c*4+3] = v.w;
                }
            } else {
                #pragma unroll
                for (int j = 0; j < 16; ++j) rb[j] = 0.0f;
            }
        } else {
            #pragma unroll
            for (int j = 0; j < 16; ++j) { ra[j] = 0.0f; rb[j] = 0.0f; }
        }
    };

    auto store_tile = [&](int buf, int t) {
        const int kb = t * 32 + kh * 16;
        float av[16];
        #pragma unroll
        for (int j = 0; j < 16; ++j) av[j] = ra[j];
        if (FUSE && kb < K) {
            #pragma unroll
            for (int j = 0; j < 16; ++j)
                av[j] = fmaxf(fmaf(av[j], ssv[kb + j], ttv[kb + j]), 0.0f);
        }
        half8 h0, h1;
        #pragma unroll
        for (int j = 0; j < 8; ++j) { h0[j] = (_Float16)av[j]; h1[j] = (_Float16)av[8 + j]; }
        *reinterpret_cast<half8*>(&As[buf][row][kh * 16])     = h0;
        *reinterpret_cast<half8*>(&As[buf][row][kh * 16 + 8]) = h1;
        #pragma unroll
        for (int j = 0; j < 8; ++j) { h0[j] = (_Float16)rb[j]; h1[j] = (_Float16)rb[8 + j]; }
        *reinterpret_cast<half8*>(&Bs[buf][row][kh * 16])     = h0;
        *reinterpret_cast<half8*>(&Bs[buf][row][kh * 16 + 8]) = h1;
    };

    // prologue: tile0 -> LDS[0]; tile1 in regs
    load_tile(0);
    store_tile(0, 0);
    load_tile(1);
    __syncthreads();

    int cur = 0;
    for (int t = 0; t < nt; ++t) {
        half8 af[4], bfr[4];
        #pragma unroll
        for (int i = 0; i < 4; ++i)
            af[i] = *reinterpret_cast<const half8*>(&As[cur][wr * 64 + i * 16 + l15][lg * 8]);
        #pragma unroll
        for (int j = 0; j < 4; ++j)
            bfr[j] = *reinterpret_cast<const half8*>(&Bs[cur][wc * 64 + j * 16 + l15][lg * 8]);
        // swapped operands: D = Bfrag x Afrag  ->  lane holds m = l15, n = lg*4 + reg
        #pragma unroll
        for (int i = 0; i < 4; ++i)
            #pragma unroll
            for (int j = 0; j < 4; ++j)
                acc[i][j] = __builtin_amdgcn_mfma_f32_16x16x32_f16(bfr[j], af[i], acc[i][j], 0, 0, 0);
        if (t + 1 < nt) {
            store_tile(cur ^ 1, t + 1);   // vmcnt-waits on regs(t+1), convert, ds_write
            load_tile(t + 2);             // issue next loads (predicated; zeros if past K)
        }
        __syncthreads();
        cur ^= 1;
    }

    // ---- epilogue: scale + bias, float4 coalesced store, optional column stats ----
    float sJ[4][4], qJ[4][4];
    if (STATS) {
        #pragma unroll
        for (int j = 0; j < 4; ++j)
            #pragma unroll
            for (int r = 0; r < 4; ++r) { sJ[j][r] = 0.f; qJ[j][r] = 0.f; }
    }
    #pragma unroll
    for (int i = 0; i < 4; ++i) {
        const int m = m0 + wr * 64 + i * 16 + l15;
        #pragma unroll
        for (int j = 0; j < 4; ++j) {
            const int nb = n0 + wc * 64 + j * 16 + lg * 4;
            float bj[4];
            if (!NCHK || nb + 4 <= N) {
                float4 bt = *reinterpret_cast<const float4*>(&bias[nb]);
                bj[0] = bt.x; bj[1] = bt.y; bj[2] = bt.z; bj[3] = bt.w;
            } else {
                #pragma unroll
                for (int r = 0; r < 4; ++r) bj[r] = (nb + r < N) ? bias[nb + r] : 0.0f;
            }
            float v[4];
            #pragma unroll
            for (int r = 0; r < 4; ++r) v[r] = fmaf(acc[i][j][r], invScale, bj[r]);
            if (!NCHK || nb + 4 <= N) {
                *reinterpret_cast<float4*>(&C[(size_t)m * N + nb]) =
                    make_float4(v[0], v[1], v[2], v[3]);
            } else {
                #pragma unroll
                for (int r = 0; r < 4; ++r)
                    if (nb + r < N) C[(size_t)m * N + nb + r] = v[r];
            }
            if (STATS) {
                #pragma unroll
                for (int r = 0; r < 4; ++r) { sJ[j][r] += v[r]; qJ[j][r] += v[r] * v[r]; }
            }
        }
    }
    if (STATS) {
        #pragma unroll
        for (int j = 0; j < 4; ++j)
            #pragma unroll
            for (int r = 0; r < 4; ++r) {
                float s = sJ[j][r], q = qJ[j][r];
                s += __shfl_xor(s, 1); s += __shfl_xor(s, 2);
                s += __shfl_xor(s, 4); s += __shfl_xor(s, 8);
                q += __shfl_xor(q, 1); q += __shfl_xor(q, 2);
                q += __shfl_xor(q, 4); q += __shfl_xor(q, 8);
                if (l15 == 0) {
                    redS[wr][wc * 64 + j * 16 + lg * 4 + r] = s;
                    redQ[wr][wc * 64 + j * 16 + lg * 4 + r] = q;
                }
            }
        __syncthreads();
        if (tid < 128) {
            atomicAdd(&sumO[n0 + tid], redS[0][tid] + redS[1][tid]);
            atomicAdd(&ssqO[n0 + tid], redQ[0][tid] + redQ[1][tid]);
        }
    }
}

// ---------------- BN finalize: s = gamma*rsqrt(var+eps)*outScale, t = (beta - mu*s̃)*outScale ----
__global__ void bn_finalize(const float* __restrict__ sum, const float* __restrict__ ssq,
                            const float* __restrict__ gamma, const float* __restrict__ beta,
                            float* __restrict__ s, float* __restrict__ t, float outScale)
{
    const int j = threadIdx.x;
    const float inv = 1.0f / (float)NBATCH;
    const float mu  = sum[j] * inv;
    float var = ssq[j] * inv - mu * mu;
    var = fmaxf(var, 0.0f);
    const float rs = 1.0f / sqrtf(var + 1e-5f);
    const float sj = gamma[j] * rs;
    s[j] = sj * outScale;
    t[j] = fmaf(-mu, sj, beta[j]) * outScale;
}

// ---------------- middle: relu(bn1(h)) -> log_map0 -> butterfly x3 -> exp_map0 -> ht
//                  + BN2 partial stats ----------------
__global__ __launch_bounds__(256)
void mid_kernel(const float* __restrict__ h, const float* __restrict__ bf,
                const float* __restrict__ s1, const float* __restrict__ t1,
                float* __restrict__ ht, float* __restrict__ sum2, float* __restrict__ ssq2)
{
    __shared__ float bsum[4][256];
    __shared__ float bssq[4][256];
    const int tid  = threadIdx.x;
    const int w    = tid >> 6;
    const int lane = tid & 63;
    const int row0 = blockIdx.x * 64 + w * 16;
    const int c0   = lane * 4;

    const float4 s1v = *reinterpret_cast<const float4*>(&s1[c0]);
    const float4 t1v = *reinterpret_cast<const float4*>(&t1[c0]);
    const float a0 = bf[2 * lane],       a1 = bf[2 * lane + 1];
    const float b0 = bf[128 + 2 * lane], b1 = bf[128 + 2 * lane + 1];
    const float a2 = bf[256 + lane],     b2 = bf[320 + lane];
    const float a3 = bf[384 + (lane >> 1)], b3 = bf[416 + (lane >> 1)];
    const float sgn = (lane & 1) ? -1.0f : 1.0f;
    const float sc  = sqrtf(1e-3f);

    float ps0 = 0, ps1 = 0, ps2 = 0, ps3 = 0;
    float q0 = 0, q1 = 0, q2 = 0, q3 = 0;

    for (int r = 0; r < 16; ++r) {
        const int row = row0 + r;
        const float4 v = *reinterpret_cast<const float4*>(&h[(size_t)row * HIDD + c0]);
        float x0 = fmaxf(fmaf(v.x, s1v.x, t1v.x), 0.0f);
        float x1 = fmaxf(fmaf(v.y, s1v.y, t1v.y), 0.0f);
        float x2 = fmaxf(fmaf(v.z, s1v.z, t1v.z), 0.0f);
        float x3 = fmaxf(fmaf(v.w, s1v.w, t1v.w), 0.0f);
        float n2 = x0 * x0 + x1 * x1 + x2 * x2 + x3 * x3;
        n2 = wave_allreduce_sum(n2);
        float sn = sc * sqrtf(n2);
        sn = fminf(fmaxf(sn, 1e-7f), 1.0f - 1e-6f);
        const float ls = atanhf(sn) / sn;
        x0 *= ls; x1 *= ls; x2 *= ls; x3 *= ls;
        const float y0 = fmaf(a0, x0,  b0 * x1);
        const float y1 = fmaf(a0, x1, -b0 * x0);
        const float y2 = fmaf(a1, x2,  b1 * x3);
        const float y3 = fmaf(a1, x3, -b1 * x2);
        const float z0 = fmaf(a2, y0,  b2 * y2);
        const float z1 = fmaf(a2, y1,  b2 * y3);
        const float z2 = fmaf(a2, y2, -b2 * y0);
        const float z3 = fmaf(a2, y3, -b2 * y1);
        const float p0 = __shfl_xor(z0, 1);
        const float p1 = __shfl_xor(z1, 1);
        const float p2 = __shfl_xor(z2, 1);
        const float p3 = __shfl_xor(z3, 1);
        const float w0 = fmaf(a3, z0, sgn * (b3 * p0));
        const float w1 = fmaf(a3, z1, sgn * (b3 * p1));
        const float w2 = fmaf(a3, z2, sgn * (b3 * p2));
        const float w3 = fmaf(a3, z3, sgn * (b3 * p3));
        float m2 = w0 * w0 + w1 * w1 + w2 * w2 + w3 * w3;
        m2 = wave_allreduce_sum(m2);
        const float sn2 = fmaxf(sc * sqrtf(m2), 1e-7f);
        const float es = tanhf(sn2) / sn2;
        const float o0 = es * w0, o1 = es * w1, o2 = es * w2, o3 = es * w3;
        *reinterpret_cast<float4*>(&ht[(size_t)row * HIDD + c0]) = make_float4(o0, o1, o2, o3);
        ps0 += o0; ps1 += o1; ps2 += o2; ps3 += o3;
        q0 += o0 * o0; q1 += o1 * o1; q2 += o2 * o2; q3 += o3 * o3;
    }

    bsum[w][c0 + 0] = ps0; bsum[w][c0 + 1] = ps1; bsum[w][c0 + 2] = ps2; bsum[w][c0 + 3] = ps3;
    bssq[w][c0 + 0] = q0;  bssq[w][c0 + 1] = q1;  bssq[w][c0 + 2] = q2;  bssq[w][c0 + 3] = q3;
    __syncthreads();
    if (tid < 256) {
        const float s = bsum[0][tid] + bsum[1][tid] + bsum[2][tid] + bsum[3][tid];
        const float q = bssq[0][tid] + bssq[1][tid] + bssq[2][tid] + bssq[3][tid];
        atomicAdd(&sum2[tid], s);
        atomicAdd(&ssq2[tid], q);
    }
}

extern "C" void kernel_launch(void* const* d_in, const int* in_sizes, int n_in,
                              void* d_out, int out_size, void* d_ws, size_t ws_size,
                              hipStream_t stream)
{
    const float* x   = (const float*)d_in[0];
    const float* w1  = (const float*)d_in[1];
    const float* b1  = (const float*)d_in[2];
    const float* g1  = (const float*)d_in[3];
    const float* be1 = (const float*)d_in[4];
    const float* bf  = (const float*)d_in[5];
    const float* g2  = (const float*)d_in[6];
    const float* be2 = (const float*)d_in[7];
    const float* w2  = (const float*)d_in[8];
    const float* b2  = (const float*)d_in[9];

    float* out = (float*)d_out;
    float* ws  = (float*)d_ws;

    float* ht   = ws;                                   // 32768*256 floats
    float* stat = ws + (size_t)NBATCH * HIDD;
    float* sum1 = stat +    0;
    float* ssq1 = stat +  256;
    float* sum2 = stat +  512;
    float* ssq2 = stat +  768;
    float* s1   = stat + 1024;
    float* t1   = stat + 1280;
    float* s2   = stat + 1536;
    float* t2   = stat + 1792;

    float* h = out;   // park h[32768][256] in d_out; dead before GEMM2 overwrites

    hipMemsetAsync(stat, 0, 1024 * sizeof(float), stream);

    // GEMM1: h = x @ fc1_w^T + fc1_b  (M=32768,N=256,K=784), fused BN1 column stats
    gemm_mfma<false, false, true><<<512, 256, 0, stream>>>(
        x, w1, b1, nullptr, nullptr, h, sum1, ssq1, NBATCH, HIDD, IND, 2, 1.0f);
    bn_finalize<<<1, 256, 0, stream>>>(sum1, ssq1, g1, be1, s1, t1, 1.0f);
    // middle: bn1+relu, log-map, butterfly x3, exp-map, BN2 stats
    mid_kernel<<<512, 256, 0, stream>>>(h, bf, s1, t1, ht, sum2, ssq2);
    // scale BN2 output by 1024 (keeps GEMM2's fp16 A-operand out of subnormals)
    bn_finalize<<<1, 256, 0, stream>>>(sum2, ssq2, g2, be2, s2, t2, 1024.0f);
    // GEMM2: out = relu(bn2(ht)) @ fc2_w^T + fc2_b  (M=32768,N=1000,K=256), un-scale in epilogue
    gemm_mfma<true, true, false><<<2048, 256, 0, stream>>>(
        ht, w2, b2, s2, t2, out, nullptr, nullptr, NBATCH, OUTD, HIDD, 8, 1.0f / 1024.0f);
}

// Round 5
// 160.608 us; speedup vs baseline: 2.8001x; 1.0391x over previous
//
#include <hip/hip_runtime.h>
#include <math.h>

#define NBATCH 32768
#define IND    784
#define KPAD   800
#define HIDD   256
#define OUTD   1000
#define OUTDP  1024

typedef _Float16 half8  __attribute__((ext_vector_type(8)));
typedef _Float16 half4v __attribute__((ext_vector_type(4)));
typedef float    floatx4 __attribute__((ext_vector_type(4)));

#define GAS __attribute__((address_space(1)))
#define LAS __attribute__((address_space(3)))

__device__ __forceinline__ void gld16(const _Float16* g, _Float16* l) {
    // async global->LDS DMA, 16B per lane; LDS dest = base + lane*16 (linear)
    __builtin_amdgcn_global_load_lds((const GAS void*)g, (LAS void*)l, 16, 0, 0);
}

__device__ __forceinline__ float wave_allreduce_sum(float v) {
    #pragma unroll
    for (int off = 32; off >= 1; off >>= 1) v += __shfl_xor(v, off);
    return v;
}

// ---------------- fp32 -> fp16 convert with zero-padding to [drows][dcols] ----------------
__global__ __launch_bounds__(256)
void cvt_fp16_pad(const float* __restrict__ src, _Float16* __restrict__ dst,
                  int srows, int scols, int drows, int dcols)
{
    const int nch = dcols >> 3;
    const long total = (long)drows * nch;
    for (long i = (long)blockIdx.x * blockDim.x + threadIdx.x; i < total;
         i += (long)gridDim.x * blockDim.x) {
        const int r  = (int)(i / nch);
        const int c8 = (int)(i % nch) << 3;
        half8 o;
        if (r < srows && c8 + 8 <= scols) {
            const float* s = &src[(size_t)r * scols + c8];
            float4 v0 = *(const float4*)s;
            float4 v1 = *(const float4*)(s + 4);
            o[0] = (_Float16)v0.x; o[1] = (_Float16)v0.y;
            o[2] = (_Float16)v0.z; o[3] = (_Float16)v0.w;
            o[4] = (_Float16)v1.x; o[5] = (_Float16)v1.y;
            o[6] = (_Float16)v1.z; o[7] = (_Float16)v1.w;
        } else {
            #pragma unroll
            for (int j = 0; j < 8; ++j)
                o[j] = (_Float16)((r < srows && c8 + j < scols)
                                  ? src[(size_t)r * scols + c8 + j] : 0.0f);
        }
        *(half8*)&dst[(size_t)r * dcols + c8] = o;
    }
}

// ================= fp16 MFMA GEMM, global_load_lds staging =================
// C[M,Nstore] = A[M,K]fp16 @ B[nbn*128,K]fp16^T * invScale + bias
// LDS layout (per buffer, 16KB): A 8 chunks of 1KB then B 8 chunks.
// Chunk c holds rows [c*16,c*16+16) of the tile; granule g (=lane) of a chunk
// holds (row_in_chunk=g>>2, k-granule=g&3) -> 8 contiguous fp16. This makes the
// DMA dest linear AND every ds_read_b128 fragment read a full-1KB permutation
// (conflict-free), with zero VALU in the staging path.
template<bool NCHK, bool STATS>
__global__ __launch_bounds__(256, 4)
void gemm16(const _Float16* __restrict__ A, const _Float16* __restrict__ Bw,
            const float* __restrict__ bias, float* __restrict__ C,
            float* __restrict__ sumO, float* __restrict__ ssqO,
            int N, int K, int nbn, float invScale)
{
    __shared__ _Float16 lds[2][8192];                       // 2 x 16KB
    __shared__ float redS[2][STATS ? 128 : 1], redQ[2][STATS ? 128 : 1];

    const int tid  = threadIdx.x;
    const int bid0 = blockIdx.x;
    const int vbid = (bid0 & 7) * ((int)gridDim.x >> 3) + (bid0 >> 3);  // XCD chunking
    const int bm = vbid / nbn, bn = vbid % nbn;
    const int m0 = bm * 128, n0 = bn * 128;
    const int lane = tid & 63;
    const int wv = tid >> 6;
    const int wr = wv >> 1, wc = wv & 1;
    const int l15 = lane & 15, lg = lane >> 4;
    const int nt = K >> 5;

    // staging: per-lane global offset for granule = lane
    const int lo = (lane >> 2) * K + (lane & 3) * 8;
    const _Float16* Ab = A  + (size_t)m0 * K + lo;
    const _Float16* Bb = Bw + (size_t)n0 * K + lo;
    const int ch0 = wv * 16 * K;            // row offset of chunk wv
    const int ch1 = (wv + 4) * 16 * K;      // row offset of chunk wv+4

    floatx4 acc[4][4];
    #pragma unroll
    for (int i = 0; i < 4; ++i)
        #pragma unroll
        for (int j = 0; j < 4; ++j) acc[i][j] = (floatx4){0.f, 0.f, 0.f, 0.f};

    auto STAGE = [&](int buf, int t) {
        const int t32 = t * 32;
        _Float16* l = &lds[buf][0];
        gld16(Ab + ch0 + t32, l + wv * 512);
        gld16(Ab + ch1 + t32, l + (wv + 4) * 512);
        gld16(Bb + ch0 + t32, l + 4096 + wv * 512);
        gld16(Bb + ch1 + t32, l + 4096 + (wv + 4) * 512);
    };

    STAGE(0, 0);
    __syncthreads();                                    // vmcnt(0) drain by compiler

    const int rdo = l15 * 32 + lg * 8;                  // fragment read offset (elems)
    int buf = 0;
    for (int t = 0; t < nt; ++t) {
        if (t + 1 < nt) STAGE(buf ^ 1, t + 1);          // loads fly under compute
        half8 af[4], bfr[4];
        #pragma unroll
        for (int i = 0; i < 4; ++i)
            af[i] = *(const half8*)&lds[buf][(wr * 4 + i) * 512 + rdo];
        #pragma unroll
        for (int j = 0; j < 4; ++j)
            bfr[j] = *(const half8*)&lds[buf][4096 + (wc * 4 + j) * 512 + rdo];
        // swapped operands: lane holds m = l15, n = lg*4 + reg  (coalesced stores)
        #pragma unroll
        for (int i = 0; i < 4; ++i)
            #pragma unroll
            for (int j = 0; j < 4; ++j)
                acc[i][j] = __builtin_amdgcn_mfma_f32_16x16x32_f16(bfr[j], af[i], acc[i][j], 0, 0, 0);
        __syncthreads();
        buf ^= 1;
    }

    // ---- epilogue: scale + bias, float4 coalesced store, optional column stats ----
    float sJ[4][4], qJ[4][4];
    if (STATS) {
        #pragma unroll
        for (int j = 0; j < 4; ++j)
            #pragma unroll
            for (int r = 0; r < 4; ++r) { sJ[j][r] = 0.f; qJ[j][r] = 0.f; }
    }
    #pragma unroll
    for (int i = 0; i < 4; ++i) {
        const int m = m0 + wr * 64 + i * 16 + l15;
        #pragma unroll
        for (int j = 0; j < 4; ++j) {
            const int nb = n0 + wc * 64 + j * 16 + lg * 4;
            float bj[4];
            if (!NCHK || nb + 4 <= N) {
                float4 bt = *reinterpret_cast<const float4*>(&bias[nb]);
                bj[0] = bt.x; bj[1] = bt.y; bj[2] = bt.z; bj[3] = bt.w;
            } else {
                #pragma unroll
                for (int r = 0; r < 4; ++r) bj[r] = (nb + r < N) ? bias[nb + r] : 0.0f;
            }
            float v[4];
            #pragma unroll
            for (int r = 0; r < 4; ++r) v[r] = fmaf(acc[i][j][r], invScale, bj[r]);
            if (!NCHK || nb + 4 <= N) {
                *reinterpret_cast<float4*>(&C[(size_t)m * N + nb]) =
                    make_float4(v[0], v[1], v[2], v[3]);
            } else {
                #pragma unroll
                for (int r = 0; r < 4; ++r)
                    if (nb + r < N) C[(size_t)m * N + nb + r] = v[r];
            }
            if (STATS) {
                #pragma unroll
                for (int r = 0; r < 4; ++r) { sJ[j][r] += v[r]; qJ[j][r] += v[r] * v[r]; }
            }
        }
    }
    if (STATS) {
        #pragma unroll
        for (int j = 0; j < 4; ++j)
            #pragma unroll
            for (int r = 0; r < 4; ++r) {
                float s = sJ[j][r], q = qJ[j][r];
                s += __shfl_xor(s, 1); s += __shfl_xor(s, 2);
                s += __shfl_xor(s, 4); s += __shfl_xor(s, 8);
                q += __shfl_xor(q, 1); q += __shfl_xor(q, 2);
                q += __shfl_xor(q, 4); q += __shfl_xor(q, 8);
                if (l15 == 0) {
                    redS[wr][wc * 64 + j * 16 + lg * 4 + r] = s;
                    redQ[wr][wc * 64 + j * 16 + lg * 4 + r] = q;
                }
            }
        __syncthreads();
        if (tid < 128) {
            atomicAdd(&sumO[n0 + tid], redS[0][tid] + redS[1][tid]);
            atomicAdd(&ssqO[n0 + tid], redQ[0][tid] + redQ[1][tid]);
        }
    }
}

// ---------------- middle: finalize BN1 (in-block) -> relu(bn1(h)) -> log_map0 ->
//                  butterfly x3 -> exp_map0 -> ht16 (x65536) + BN2 raw stats ----------------
__global__ __launch_bounds__(256)
void mid_kernel(const float* __restrict__ h, const float* __restrict__ bfp,
                const float* __restrict__ sum1, const float* __restrict__ ssq1,
                const float* __restrict__ g1, const float* __restrict__ be1,
                _Float16* __restrict__ ht16, float* __restrict__ sum2, float* __restrict__ ssq2)
{
    __shared__ float s1sh[256], t1sh[256];
    __shared__ float bsum[4][256], bssq[4][256];
    const int tid  = threadIdx.x;
    {
        const float inv = 1.0f / (float)NBATCH;
        const float mu  = sum1[tid] * inv;
        const float var = fmaxf(ssq1[tid] * inv - mu * mu, 0.0f);
        const float rs  = 1.0f / sqrtf(var + 1e-5f);
        const float sj  = g1[tid] * rs;
        s1sh[tid] = sj;
        t1sh[tid] = fmaf(-mu, sj, be1[tid]);
    }
    __syncthreads();

    const int w    = tid >> 6;
    const int lane = tid & 63;
    const int row0 = blockIdx.x * 64 + w * 16;
    const int c0   = lane * 4;

    const float4 s1v = *reinterpret_cast<const float4*>(&s1sh[c0]);
    const float4 t1v = *reinterpret_cast<const float4*>(&t1sh[c0]);
    const float a0 = bfp[2 * lane],       a1 = bfp[2 * lane + 1];
    const float b0 = bfp[128 + 2 * lane], b1 = bfp[128 + 2 * lane + 1];
    const float a2 = bfp[256 + lane],     b2 = bfp[320 + lane];
    const float a3 = bfp[384 + (lane >> 1)], b3 = bfp[416 + (lane >> 1)];
    const float sgn = (lane & 1) ? -1.0f : 1.0f;
    const float sc  = sqrtf(1e-3f);

    float ps0 = 0, ps1 = 0, ps2 = 0, ps3 = 0;
    float q0 = 0, q1 = 0, q2 = 0, q3 = 0;

    for (int r = 0; r < 16; ++r) {
        const int row = row0 + r;
        const float4 v = *reinterpret_cast<const float4*>(&h[(size_t)row * HIDD + c0]);
        float x0 = fmaxf(fmaf(v.x, s1v.x, t1v.x), 0.0f);
        float x1 = fmaxf(fmaf(v.y, s1v.y, t1v.y), 0.0f);
        float x2 = fmaxf(fmaf(v.z, s1v.z, t1v.z), 0.0f);
        float x3 = fmaxf(fmaf(v.w, s1v.w, t1v.w), 0.0f);
        float n2 = x0 * x0 + x1 * x1 + x2 * x2 + x3 * x3;
        n2 = wave_allreduce_sum(n2);
        float sn = sc * sqrtf(n2);
        sn = fminf(fmaxf(sn, 1e-7f), 1.0f - 1e-6f);
        const float ls = atanhf(sn) / sn;
        x0 *= ls; x1 *= ls; x2 *= ls; x3 *= ls;
        const float y0 = fmaf(a0, x0,  b0 * x1);
        const float y1 = fmaf(a0, x1, -b0 * x0);
        const float y2 = fmaf(a1, x2,  b1 * x3);
        const float y3 = fmaf(a1, x3, -b1 * x2);
        const float z0 = fmaf(a2, y0,  b2 * y2);
        const float z1 = fmaf(a2, y1,  b2 * y3);
        const float z2 = fmaf(a2, y2, -b2 * y0);
        const float z3 = fmaf(a2, y3, -b2 * y1);
        const float p0 = __shfl_xor(z0, 1);
        const float p1 = __shfl_xor(z1, 1);
        const float p2 = __shfl_xor(z2, 1);
        const float p3 = __shfl_xor(z3, 1);
        const float w0 = fmaf(a3, z0, sgn * (b3 * p0));
        const float w1 = fmaf(a3, z1, sgn * (b3 * p1));
        const float w2 = fmaf(a3, z2, sgn * (b3 * p2));
        const float w3 = fmaf(a3, z3, sgn * (b3 * p3));
        float m2 = w0 * w0 + w1 * w1 + w2 * w2 + w3 * w3;
        m2 = wave_allreduce_sum(m2);
        const float sn2 = fmaxf(sc * sqrtf(m2), 1e-7f);
        const float es = tanhf(sn2) / sn2;
        const float o0 = es * w0, o1 = es * w1, o2 = es * w2, o3 = es * w3;
        half4v hv;
        hv[0] = (_Float16)(o0 * 65536.0f); hv[1] = (_Float16)(o1 * 65536.0f);
        hv[2] = (_Float16)(o2 * 65536.0f); hv[3] = (_Float16)(o3 * 65536.0f);
        *reinterpret_cast<half4v*>(&ht16[(size_t)row * HIDD + c0]) = hv;
        ps0 += o0; ps1 += o1; ps2 += o2; ps3 += o3;
        q0 += o0 * o0; q1 += o1 * o1; q2 += o2 * o2; q3 += o3 * o3;
    }

    bsum[w][c0 + 0] = ps0; bsum[w][c0 + 1] = ps1; bsum[w][c0 + 2] = ps2; bsum[w][c0 + 3] = ps3;
    bssq[w][c0 + 0] = q0;  bssq[w][c0 + 1] = q1;  bssq[w][c0 + 2] = q2;  bssq[w][c0 + 3] = q3;
    __syncthreads();
    if (tid < 256) {
        const float s = bsum[0][tid] + bsum[1][tid] + bsum[2][tid] + bsum[3][tid];
        const float q = bssq[0][tid] + bssq[1][tid] + bssq[2][tid] + bssq[3][tid];
        atomicAdd(&sum2[tid], s);
        atomicAdd(&ssq2[tid], q);
    }
}

// ---------------- finalize BN2 (in-block) + a2 = fp16( relu(bn2(ht)) * 1024 ) ----------------
// ht16 holds ht*65536; s folded: s2*1024/65536, t folded: t2*1024.
__global__ __launch_bounds__(256)
void bn2relu_kernel(const _Float16* __restrict__ ht16,
                    const float* __restrict__ sum2, const float* __restrict__ ssq2,
                    const float* __restrict__ g2, const float* __restrict__ be2,
                    _Float16* __restrict__ a2)
{
    __shared__ float sf[256], tf[256];
    const int tid = threadIdx.x;
    {
        const float inv = 1.0f / (float)NBATCH;
        const float mu  = sum2[tid] * inv;
        const float var = fmaxf(ssq2[tid] * inv - mu * mu, 0.0f);
        const float rs  = 1.0f / sqrtf(var + 1e-5f);
        const float sj  = g2[tid] * rs;
        sf[tid] = sj * (1024.0f / 65536.0f);
        tf[tid] = fmaf(-mu, sj, be2[tid]) * 1024.0f;
    }
    __syncthreads();

    const long nch = (long)NBATCH * (HIDD / 8);
    for (long i = (long)blockIdx.x * blockDim.x + tid; i < nch;
         i += (long)gridDim.x * blockDim.x) {
        const int c8 = ((int)(i & 31)) << 3;
        half8 v = *(const half8*)&ht16[i * 8];
        half8 o;
        #pragma unroll
        for (int j = 0; j < 8; ++j) {
            const float f = fmaf((float)v[j], sf[c8 + j], tf[c8 + j]);
            o[j] = (_Float16)fmaxf(f, 0.0f);
        }
        *(half8*)&a2[i * 8] = o;
    }
}

extern "C" void kernel_launch(void* const* d_in, const int* in_sizes, int n_in,
                              void* d_out, int out_size, void* d_ws, size_t ws_size,
                              hipStream_t stream)
{
    const float* x   = (const float*)d_in[0];
    const float* w1  = (const float*)d_in[1];
    const float* b1  = (const float*)d_in[2];
    const float* g1  = (const float*)d_in[3];
    const float* be1 = (const float*)d_in[4];
    const float* bfp = (const float*)d_in[5];
    const float* g2  = (const float*)d_in[6];
    const float* be2 = (const float*)d_in[7];
    const float* w2  = (const float*)d_in[8];
    const float* b2  = (const float*)d_in[9];

    float* out = (float*)d_out;
    float* ws  = (float*)d_ws;

    // d_out parking (all dead before GEMM2 overwrites the full output):
    float*    h    = out;                                   //  8.39M f32
    _Float16* x16  = (_Float16*)(out + 8388608);            // 32768 x 800 fp16
    _Float16* ht16 = (_Float16*)(out + 21495808);           // 32768 x 256 fp16
    _Float16* w1h  = (_Float16*)(out + 25690112);           //   256 x 800 fp16
    // ws (17.3 MB): read by GEMM2 while it writes d_out
    _Float16* a2   = (_Float16*)ws;                         // 32768 x 256 fp16
    _Float16* w2h  = (_Float16*)(ws + 4194304);             //  1024 x 256 fp16
    float*    stat = ws + 4194304 + 131072;
    float* sum1 = stat +   0;
    float* ssq1 = stat + 256;
    float* sum2 = stat + 512;
    float* ssq2 = stat + 768;

    hipMemsetAsync(stat, 0, 1024 * sizeof(float), stream);

    // fp16 conversions (BW-bound passes)
    cvt_fp16_pad<<<2048, 256, 0, stream>>>(x,  x16, NBATCH, IND, NBATCH, KPAD);
    cvt_fp16_pad<<<128,  256, 0, stream>>>(w1, w1h, HIDD, IND, HIDD, KPAD);
    cvt_fp16_pad<<<128,  256, 0, stream>>>(w2, w2h, OUTD, HIDD, OUTDP, HIDD);

    // GEMM1: h = x16 @ w1h^T + b1  (M=32768, N=256, K=800) + BN1 column stats
    gemm16<false, true><<<512, 256, 0, stream>>>(
        x16, w1h, b1, h, sum1, ssq1, HIDD, KPAD, 2, 1.0f);

    // middle: BN1 finalize + bn1/relu + log-map + butterfly x3 + exp-map -> ht16, BN2 stats
    mid_kernel<<<512, 256, 0, stream>>>(h, bfp, sum1, ssq1, g1, be1, ht16, sum2, ssq2);

    // BN2 finalize + relu -> a2 (fp16, x1024)
    bn2relu_kernel<<<2048, 256, 0, stream>>>(ht16, sum2, ssq2, g2, be2, a2);

    // GEMM2: out = a2 @ w2h^T / 1024 + b2  (M=32768, N=1000, K=256)
    gemm16<true, false><<<2048, 256, 0, stream>>>(
        a2, w2h, b2, out, nullptr, nullptr, OUTD, HIDD, 8, 1.0f / 1024.0f);
}

// Round 6
// 133.080 us; speedup vs baseline: 3.3794x; 1.2069x over previous
//
#include <hip/hip_runtime.h>
#include <math.h>

#define NBATCH 32768
#define IND    784
#define KPAD1  800
#define HIDD   256
#define OUTD   1000
#define OUTDP  1024

typedef _Float16 half8  __attribute__((ext_vector_type(8)));
typedef _Float16 half4v __attribute__((ext_vector_type(4)));
typedef float    floatx4 __attribute__((ext_vector_type(4)));

#define GAS __attribute__((address_space(1)))
#define LAS __attribute__((address_space(3)))

__device__ __forceinline__ void gld16(const void* g, void* l) {
    // async global->LDS DMA: 16B per lane, LDS dest = wave-uniform base + lane*16
    __builtin_amdgcn_global_load_lds((const GAS void*)g, (LAS void*)l, 16, 0, 0);
}

__device__ __forceinline__ float wave_allreduce_sum(float v) {
    #pragma unroll
    for (int off = 32; off >= 1; off >>= 1) v += __shfl_xor(v, off);
    return v;
}

// ---------------- prep: w1 -> w1h (pad K to 800), w2 -> w2h (pad N to 1024), zero stats ----------
__global__ __launch_bounds__(256)
void prep_kernel(const float* __restrict__ w1, _Float16* __restrict__ w1h,
                 const float* __restrict__ w2, _Float16* __restrict__ w2h,
                 float* __restrict__ stat)
{
    const int tid = threadIdx.x;
    if (blockIdx.x == 0) {
        for (int j = tid; j < 1024 + 16; j += 256) stat[j] = 0.0f;   // sums/ssqs + zbuf
    }
    const int NW1 = HIDD * (KPAD1 / 8);     // 25600 granules
    const int NW2 = OUTDP * (HIDD / 8);     // 32768 granules
    for (int i = blockIdx.x * 256 + tid; i < NW1 + NW2; i += (int)gridDim.x * 256) {
        half8 o;
        if (i < NW1) {
            const int r = i / (KPAD1 / 8), c8 = (i % (KPAD1 / 8)) * 8;
            if (c8 + 8 <= IND) {
                const float* s = &w1[(size_t)r * IND + c8];
                float4 v0 = *(const float4*)s, v1 = *(const float4*)(s + 4);
                o[0]=(_Float16)v0.x; o[1]=(_Float16)v0.y; o[2]=(_Float16)v0.z; o[3]=(_Float16)v0.w;
                o[4]=(_Float16)v1.x; o[5]=(_Float16)v1.y; o[6]=(_Float16)v1.z; o[7]=(_Float16)v1.w;
            } else {
                #pragma unroll
                for (int j = 0; j < 8; ++j) o[j] = (_Float16)0.0f;
            }
            *(half8*)&w1h[(size_t)r * KPAD1 + c8] = o;
        } else {
            const int k = i - NW1;
            const int r = k >> 5, c8 = (k & 31) * 8;
            if (r < OUTD) {
                const float* s = &w2[(size_t)r * HIDD + c8];
                float4 v0 = *(const float4*)s, v1 = *(const float4*)(s + 4);
                o[0]=(_Float16)v0.x; o[1]=(_Float16)v0.y; o[2]=(_Float16)v0.z; o[3]=(_Float16)v0.w;
                o[4]=(_Float16)v1.x; o[5]=(_Float16)v1.y; o[6]=(_Float16)v1.z; o[7]=(_Float16)v1.w;
            } else {
                #pragma unroll
                for (int j = 0; j < 8; ++j) o[j] = (_Float16)0.0f;
            }
            *(half8*)&w2h[(size_t)r * HIDD + c8] = o;
        }
    }
}

// ================= GEMM1: h = x(fp32,K=784) @ w1h(fp16,K=800)^T + b1, BN1 stats =================
// A staged as fp32 via gld16 (16 chunks of 8 rows x 32k, 3-bit XOR source swizzle -> 2-way free),
// converted fp32->fp16 at fragment read. B fp16 (8 chunks of 16 rows x 32k, 2-bit XOR swizzle).
// Tail k>=784 staged from a zero buffer (per-lane source redirect).
__global__ __launch_bounds__(256, 2)
void gemm1_kernel(const float* __restrict__ x, const _Float16* __restrict__ w1h,
                  const float* __restrict__ b1, const float* __restrict__ zbuf,
                  float* __restrict__ h, float* __restrict__ sum1, float* __restrict__ ssq1)
{
    __shared__ __align__(16) float    ldsA[2][4096];   // 2 x 16KB
    __shared__ __align__(16) _Float16 ldsB[2][4096];   // 2 x 8KB
    __shared__ float redS[2][128], redQ[2][128];

    const int tid  = threadIdx.x;
    const int bid0 = blockIdx.x;
    const int vbid = (bid0 & 7) * 64 + (bid0 >> 3);    // XCD chunking (grid 512)
    const int bm = vbid >> 1, bn = vbid & 1;
    const int m0 = bm * 128, n0 = bn * 128;
    const int lane = tid & 63, wv = tid >> 6;
    const int wr = wv >> 1, wc = wv & 1;
    const int l15 = lane & 15, lg = lane >> 4;
    const int e7 = l15 & 7, e3 = l15 & 3;

    // staging lane geometry (source pre-swizzled; LDS dest linear)
    const int arow = lane >> 3, agp = (lane & 7) ^ arow;        // fp32: granule = 4 floats
    const int brow = lane >> 2, bgp = (lane & 3) ^ (brow & 3);  // fp16: granule = 8 halves
    const float*    Ab = x   + (size_t)(m0 + arow) * IND   + agp * 4;
    const _Float16* Bb = w1h + (size_t)(n0 + brow) * KPAD1 + bgp * 8;

    floatx4 acc[4][4];
    #pragma unroll
    for (int i = 0; i < 4; ++i)
        #pragma unroll
        for (int j = 0; j < 4; ++j) acc[i][j] = (floatx4){0.f, 0.f, 0.f, 0.f};

    auto STAGE = [&](int buf, int t) {
        const int t32 = t * 32;
        const bool aok = (t32 + agp * 4) < IND;
        #pragma unroll
        for (int c = 0; c < 4; ++c) {
            const int ch = wv + c * 4;                  // A chunks 0..15
            const float* s = aok ? (Ab + (size_t)ch * 8 * IND + t32) : zbuf;
            gld16(s, &ldsA[buf][ch * 256]);
        }
        #pragma unroll
        for (int c = 0; c < 2; ++c) {
            const int ch = wv + c * 4;                  // B chunks 0..7
            gld16(Bb + (size_t)ch * 16 * KPAD1 + t32, &ldsB[buf][ch * 512]);
        }
    };

    STAGE(0, 0);
    __syncthreads();

    int buf = 0;
    const int nt = KPAD1 / 32;                          // 25
    for (int t = 0; t < nt; ++t) {
        if (t + 1 < nt) STAGE(buf ^ 1, t + 1);
        half8 af[4], bfr[4];
        #pragma unroll
        for (int i = 0; i < 4; ++i) {
            const int rc = wr * 8 + i * 2 + (l15 >> 3);
            const float* base = &ldsA[buf][rc * 256 + e7 * 32];
            float4 va = *(const float4*)(base + (((2 * lg)     ^ e7) * 4));
            float4 vb = *(const float4*)(base + (((2 * lg + 1) ^ e7) * 4));
            half8 hv;
            hv[0]=(_Float16)va.x; hv[1]=(_Float16)va.y; hv[2]=(_Float16)va.z; hv[3]=(_Float16)va.w;
            hv[4]=(_Float16)vb.x; hv[5]=(_Float16)vb.y; hv[6]=(_Float16)vb.z; hv[7]=(_Float16)vb.w;
            af[i] = hv;
        }
        #pragma unroll
        for (int j = 0; j < 4; ++j)
            bfr[j] = *(const half8*)&ldsB[buf][(wc * 4 + j) * 512 + l15 * 32 + ((lg ^ e3) * 8)];
        #pragma unroll
        for (int i = 0; i < 4; ++i)
            #pragma unroll
            for (int j = 0; j < 4; ++j)
                acc[i][j] = __builtin_amdgcn_mfma_f32_16x16x32_f16(bfr[j], af[i], acc[i][j], 0, 0, 0);
        __syncthreads();
        buf ^= 1;
    }

    // epilogue: bias, float4 store, column stats
    float sJ[4][4], qJ[4][4];
    #pragma unroll
    for (int j = 0; j < 4; ++j)
        #pragma unroll
        for (int r = 0; r < 4; ++r) { sJ[j][r] = 0.f; qJ[j][r] = 0.f; }
    #pragma unroll
    for (int i = 0; i < 4; ++i) {
        const int m = m0 + wr * 64 + i * 16 + l15;
        #pragma unroll
        for (int j = 0; j < 4; ++j) {
            const int nb = n0 + wc * 64 + j * 16 + lg * 4;
            float4 bt = *reinterpret_cast<const float4*>(&b1[nb]);
            float v[4] = {acc[i][j][0] + bt.x, acc[i][j][1] + bt.y,
                          acc[i][j][2] + bt.z, acc[i][j][3] + bt.w};
            *reinterpret_cast<float4*>(&h[(size_t)m * HIDD + nb]) =
                make_float4(v[0], v[1], v[2], v[3]);
            #pragma unroll
            for (int r = 0; r < 4; ++r) { sJ[j][r] += v[r]; qJ[j][r] += v[r] * v[r]; }
        }
    }
    #pragma unroll
    for (int j = 0; j < 4; ++j)
        #pragma unroll
        for (int r = 0; r < 4; ++r) {
            float s = sJ[j][r], q = qJ[j][r];
            s += __shfl_xor(s, 1); s += __shfl_xor(s, 2);
            s += __shfl_xor(s, 4); s += __shfl_xor(s, 8);
            q += __shfl_xor(q, 1); q += __shfl_xor(q, 2);
            q += __shfl_xor(q, 4); q += __shfl_xor(q, 8);
            if (l15 == 0) {
                redS[wr][wc * 64 + j * 16 + lg * 4 + r] = s;
                redQ[wr][wc * 64 + j * 16 + lg * 4 + r] = q;
            }
        }
    __syncthreads();
    if (tid < 128) {
        atomicAdd(&sum1[n0 + tid], redS[0][tid] + redS[1][tid]);
        atomicAdd(&ssq1[n0 + tid], redQ[0][tid] + redQ[1][tid]);
    }
}

// ---------------- middle: BN1 finalize -> relu(bn1(h)) -> log_map0 -> butterfly x3 ->
//                  exp_map0 -> ht16 (x65536) + BN2 raw stats ----------------
__global__ __launch_bounds__(256)
void mid_kernel(const float* __restrict__ h, const float* __restrict__ bfp,
                const float* __restrict__ sum1, const float* __restrict__ ssq1,
                const float* __restrict__ g1, const float* __restrict__ be1,
                _Float16* __restrict__ ht16, float* __restrict__ sum2, float* __restrict__ ssq2)
{
    __shared__ float s1sh[256], t1sh[256];
    __shared__ float bsum[4][256], bssq[4][256];
    const int tid  = threadIdx.x;
    {
        const float inv = 1.0f / (float)NBATCH;
        const float mu  = sum1[tid] * inv;
        const float var = fmaxf(ssq1[tid] * inv - mu * mu, 0.0f);
        const float rs  = 1.0f / sqrtf(var + 1e-5f);
        const float sj  = g1[tid] * rs;
        s1sh[tid] = sj;
        t1sh[tid] = fmaf(-mu, sj, be1[tid]);
    }
    __syncthreads();

    const int w    = tid >> 6;
    const int lane = tid & 63;
    const int row0 = blockIdx.x * 64 + w * 16;
    const int c0   = lane * 4;

    const float4 s1v = *reinterpret_cast<const float4*>(&s1sh[c0]);
    const float4 t1v = *reinterpret_cast<const float4*>(&t1sh[c0]);
    const float a0 = bfp[2 * lane],       a1 = bfp[2 * lane + 1];
    const float b0 = bfp[128 + 2 * lane], b1 = bfp[128 + 2 * lane + 1];
    const float a2 = bfp[256 + lane],     b2 = bfp[320 + lane];
    const float a3 = bfp[384 + (lane >> 1)], b3 = bfp[416 + (lane >> 1)];
    const float sgn = (lane & 1) ? -1.0f : 1.0f;
    const float sc  = sqrtf(1e-3f);

    float ps0 = 0, ps1 = 0, ps2 = 0, ps3 = 0;
    float q0 = 0, q1 = 0, q2 = 0, q3 = 0;

    for (int r = 0; r < 16; ++r) {
        const int row = row0 + r;
        const float4 v = *reinterpret_cast<const float4*>(&h[(size_t)row * HIDD + c0]);
        float x0 = fmaxf(fmaf(v.x, s1v.x, t1v.x), 0.0f);
        float x1 = fmaxf(fmaf(v.y, s1v.y, t1v.y), 0.0f);
        float x2 = fmaxf(fmaf(v.z, s1v.z, t1v.z), 0.0f);
        float x3 = fmaxf(fmaf(v.w, s1v.w, t1v.w), 0.0f);
        float n2 = x0 * x0 + x1 * x1 + x2 * x2 + x3 * x3;
        n2 = wave_allreduce_sum(n2);
        float sn = sc * sqrtf(n2);
        sn = fminf(fmaxf(sn, 1e-7f), 1.0f - 1e-6f);
        const float ls = atanhf(sn) / sn;
        x0 *= ls; x1 *= ls; x2 *= ls; x3 *= ls;
        const float y0 = fmaf(a0, x0,  b0 * x1);
        const float y1 = fmaf(a0, x1, -b0 * x0);
        const float y2 = fmaf(a1, x2,  b1 * x3);
        const float y3 = fmaf(a1, x3, -b1 * x2);
        const float z0 = fmaf(a2, y0,  b2 * y2);
        const float z1 = fmaf(a2, y1,  b2 * y3);
        const float z2 = fmaf(a2, y2, -b2 * y0);
        const float z3 = fmaf(a2, y3, -b2 * y1);
        const float p0 = __shfl_xor(z0, 1);
        const float p1 = __shfl_xor(z1, 1);
        const float p2 = __shfl_xor(z2, 1);
        const float p3 = __shfl_xor(z3, 1);
        const float w0 = fmaf(a3, z0, sgn * (b3 * p0));
        const float w1 = fmaf(a3, z1, sgn * (b3 * p1));
        const float w2 = fmaf(a3, z2, sgn * (b3 * p2));
        const float w3 = fmaf(a3, z3, sgn * (b3 * p3));
        float m2 = w0 * w0 + w1 * w1 + w2 * w2 + w3 * w3;
        m2 = wave_allreduce_sum(m2);
        const float sn2 = fmaxf(sc * sqrtf(m2), 1e-7f);
        const float es = tanhf(sn2) / sn2;
        const float o0 = es * w0, o1 = es * w1, o2 = es * w2, o3 = es * w3;
        half4v hv;
        hv[0] = (_Float16)(o0 * 65536.0f); hv[1] = (_Float16)(o1 * 65536.0f);
        hv[2] = (_Float16)(o2 * 65536.0f); hv[3] = (_Float16)(o3 * 65536.0f);
        *reinterpret_cast<half4v*>(&ht16[(size_t)row * HIDD + c0]) = hv;
        ps0 += o0; ps1 += o1; ps2 += o2; ps3 += o3;
        q0 += o0 * o0; q1 += o1 * o1; q2 += o2 * o2; q3 += o3 * o3;
    }

    bsum[w][c0 + 0] = ps0; bsum[w][c0 + 1] = ps1; bsum[w][c0 + 2] = ps2; bsum[w][c0 + 3] = ps3;
    bssq[w][c0 + 0] = q0;  bssq[w][c0 + 1] = q1;  bssq[w][c0 + 2] = q2;  bssq[w][c0 + 3] = q3;
    __syncthreads();
    if (tid < 256) {
        const float s = bsum[0][tid] + bsum[1][tid] + bsum[2][tid] + bsum[3][tid];
        const float q = bssq[0][tid] + bssq[1][tid] + bssq[2][tid] + bssq[3][tid];
        atomicAdd(&sum2[tid], s);
        atomicAdd(&ssq2[tid], q);
    }
}

// ================= GEMM2: out = relu(bn2(ht)) @ w2h^T + b2, BN2 fused at fragment read =========
// A = ht16 (holds ht*65536). Prologue finalizes BN2 into sf/tf (folded scales).
// af = fp16( relu( sf[k]*raw + tf[k] ) )  -> values are relu(bn2)*1024; epilogue * 1/1024.
__global__ __launch_bounds__(256, 3)
void gemm2_kernel(const _Float16* __restrict__ ht16, const _Float16* __restrict__ w2h,
                  const float* __restrict__ b2,
                  const float* __restrict__ sum2, const float* __restrict__ ssq2,
                  const float* __restrict__ g2, const float* __restrict__ be2,
                  float* __restrict__ out)
{
    __shared__ __align__(16) _Float16 ldsA[2][4096];   // 2 x 8KB
    __shared__ __align__(16) _Float16 ldsB[2][4096];
    __shared__ float sf[256], tf[256];

    const int tid = threadIdx.x;
    {
        const float inv = 1.0f / (float)NBATCH;
        const float mu  = sum2[tid] * inv;
        const float var = fmaxf(ssq2[tid] * inv - mu * mu, 0.0f);
        const float rs  = 1.0f / sqrtf(var + 1e-5f);
        const float sj  = g2[tid] * rs;
        sf[tid] = sj * (1024.0f / 65536.0f);
        tf[tid] = fmaf(-mu, sj, be2[tid]) * 1024.0f;
    }

    const int bid0 = blockIdx.x;
    const int vbid = (bid0 & 7) * 256 + (bid0 >> 3);   // XCD chunking (grid 2048)
    const int bm = vbid >> 3, bn = vbid & 7;
    const int m0 = bm * 128, n0 = bn * 128;
    const int lane = tid & 63, wv = tid >> 6;
    const int wr = wv >> 1, wc = wv & 1;
    const int l15 = lane & 15, lg = lane >> 4;
    const int e3 = l15 & 3;

    const int srow = lane >> 2, sgp = (lane & 3) ^ (srow & 3);
    const _Float16* Ab = ht16 + (size_t)(m0 + srow) * HIDD + sgp * 8;
    const _Float16* Bb = w2h  + (size_t)(n0 + srow) * HIDD + sgp * 8;

    floatx4 acc[4][4];
    #pragma unroll
    for (int i = 0; i < 4; ++i)
        #pragma unroll
        for (int j = 0; j < 4; ++j) acc[i][j] = (floatx4){0.f, 0.f, 0.f, 0.f};

    auto STAGE = [&](int buf, int t) {
        const int t32 = t * 32;
        #pragma unroll
        for (int c = 0; c < 2; ++c) {
            const int ch = wv + c * 4;                  // chunks 0..7 (16 rows x 32k)
            gld16(Ab + (size_t)ch * 16 * HIDD + t32, &ldsA[buf][ch * 512]);
            gld16(Bb + (size_t)ch * 16 * HIDD + t32, &ldsB[buf][ch * 512]);
        }
    };

    STAGE(0, 0);
    __syncthreads();                                    // also fences sf/tf

    int buf = 0;
    const int nt = HIDD / 32;                           // 8
    for (int t = 0; t < nt; ++t) {
        if (t + 1 < nt) STAGE(buf ^ 1, t + 1);
        const int kb = t * 32 + lg * 8;
        float4 s0 = *(const float4*)&sf[kb], s1 = *(const float4*)&sf[kb + 4];
        float4 t0 = *(const float4*)&tf[kb], t1 = *(const float4*)&tf[kb + 4];
        half8 af[4], bfr[4];
        #pragma unroll
        for (int i = 0; i < 4; ++i) {
            half8 v = *(const half8*)&ldsA[buf][(wr * 4 + i) * 512 + l15 * 32 + ((lg ^ e3) * 8)];
            half8 hv;
            hv[0] = (_Float16)fmaxf(fmaf((float)v[0], s0.x, t0.x), 0.0f);
            hv[1] = (_Float16)fmaxf(fmaf((float)v[1], s0.y, t0.y), 0.0f);
            hv[2] = (_Float16)fmaxf(fmaf((float)v[2], s0.z, t0.z), 0.0f);
            hv[3] = (_Float16)fmaxf(fmaf((float)v[3], s0.w, t0.w), 0.0f);
            hv[4] = (_Float16)fmaxf(fmaf((float)v[4], s1.x, t1.x), 0.0f);
            hv[5] = (_Float16)fmaxf(fmaf((float)v[5], s1.y, t1.y), 0.0f);
            hv[6] = (_Float16)fmaxf(fmaf((float)v[6], s1.z, t1.z), 0.0f);
            hv[7] = (_Float16)fmaxf(fmaf((float)v[7], s1.w, t1.w), 0.0f);
            af[i] = hv;
        }
        #pragma unroll
        for (int j = 0; j < 4; ++j)
            bfr[j] = *(const half8*)&ldsB[buf][(wc * 4 + j) * 512 + l15 * 32 + ((lg ^ e3) * 8)];
        #pragma unroll
        for (int i = 0; i < 4; ++i)
            #pragma unroll
            for (int j = 0; j < 4; ++j)
                acc[i][j] = __builtin_amdgcn_mfma_f32_16x16x32_f16(bfr[j], af[i], acc[i][j], 0, 0, 0);
        __syncthreads();
        buf ^= 1;
    }

    // epilogue: /1024, + bias, bounds-checked float4 store (N=1000 < padded 1024)
    const float invScale = 1.0f / 1024.0f;
    #pragma unroll
    for (int i = 0; i < 4; ++i) {
        const int m = m0 + wr * 64 + i * 16 + l15;
        #pragma unroll
        for (int j = 0; j < 4; ++j) {
            const int nb = n0 + wc * 64 + j * 16 + lg * 4;
            float bj[4];
            if (nb + 4 <= OUTD) {
                float4 bt = *reinterpret_cast<const float4*>(&b2[nb]);
                bj[0] = bt.x; bj[1] = bt.y; bj[2] = bt.z; bj[3] = bt.w;
            } else {
                #pragma unroll
                for (int r = 0; r < 4; ++r) bj[r] = (nb + r < OUTD) ? b2[nb + r] : 0.0f;
            }
            float v[4];
            #pragma unroll
            for (int r = 0; r < 4; ++r) v[r] = fmaf(acc[i][j][r], invScale, bj[r]);
            if (nb + 4 <= OUTD) {
                *reinterpret_cast<float4*>(&out[(size_t)m * OUTD + nb]) =
                    make_float4(v[0], v[1], v[2], v[3]);
            } else {
                #pragma unroll
                for (int r = 0; r < 4; ++r)
                    if (nb + r < OUTD) out[(size_t)m * OUTD + nb + r] = v[r];
            }
        }
    }
}

extern "C" void kernel_launch(void* const* d_in, const int* in_sizes, int n_in,
                              void* d_out, int out_size, void* d_ws, size_t ws_size,
                              hipStream_t stream)
{
    const float* x   = (const float*)d_in[0];
    const float* w1  = (const float*)d_in[1];
    const float* b1  = (const float*)d_in[2];
    const float* g1  = (const float*)d_in[3];
    const float* be1 = (const float*)d_in[4];
    const float* bfp = (const float*)d_in[5];
    const float* g2  = (const float*)d_in[6];
    const float* be2 = (const float*)d_in[7];
    const float* w2  = (const float*)d_in[8];
    const float* b2  = (const float*)d_in[9];

    float* out = (float*)d_out;
    char*  wsb = (char*)d_ws;

    // ws layout (all 16B aligned): ht16 | w1h | w2h | stats+zbuf   (~17.7 MB)
    _Float16* ht16 = (_Float16*)(wsb);                    // 32768 x 256 fp16
    _Float16* w1h  = (_Float16*)(wsb + 16777216);         //   256 x 800 fp16
    _Float16* w2h  = (_Float16*)(wsb + 17186816);         //  1024 x 256 fp16
    float*    stat = (float*)  (wsb + 17711104);          // 4 x 256 stats + 16 zbuf
    float* sum1 = stat;
    float* ssq1 = stat + 256;
    float* sum2 = stat + 512;
    float* ssq2 = stat + 768;
    float* zbuf = stat + 1024;

    float* h = out;   // park h[32768][256] fp32 in d_out; consumed by mid before GEMM2 overwrites

    // 1) weight conversion + stats zeroing
    prep_kernel<<<232, 256, 0, stream>>>(w1, w1h, w2, w2h, stat);
    // 2) GEMM1 (direct fp32 x staging) + BN1 stats
    gemm1_kernel<<<512, 256, 0, stream>>>(x, w1h, b1, zbuf, h, sum1, ssq1);
    // 3) BN1 finalize + relu + log-map + butterfly x3 + exp-map -> ht16, BN2 stats
    mid_kernel<<<512, 256, 0, stream>>>(h, bfp, sum1, ssq1, g1, be1, ht16, sum2, ssq2);
    // 4) GEMM2 with fused BN2+relu at fragment read
    gemm2_kernel<<<2048, 256, 0, stream>>>(ht16, w2h, b2, sum2, ssq2, g2, be2, out);
}

// Round 8
// 129.384 us; speedup vs baseline: 3.4759x; 1.0286x over previous
//
#include <hip/hip_runtime.h>
#include <math.h>

#define NBATCH 32768
#define IND    784
#define KPAD1  800
#define HIDD   256
#define OUTD   1000
#define OUTDP  1024

typedef _Float16 half8  __attribute__((ext_vector_type(8)));
typedef _Float16 half4v __attribute__((ext_vector_type(4)));
typedef float    floatx4 __attribute__((ext_vector_type(4)));

#define GAS __attribute__((address_space(1)))
#define LAS __attribute__((address_space(3)))

// counted-vmcnt wait + lgkmcnt(0) (raw s_barrier does NOT fence LDS ops — ds_write data
// deps MUST be lgkmcnt-drained before the barrier, ISA §8) + raw barrier + scheduler pin.
// lgkmcnt(0) is free at loop barriers: all ds_reads already consumed by MFMA data deps.
#define WAITVM_BAR(N)                                                      \
    asm volatile("s_waitcnt vmcnt(" #N ") lgkmcnt(0)" ::: "memory");       \
    __builtin_amdgcn_s_barrier();                                          \
    __builtin_amdgcn_sched_barrier(0)

__device__ __forceinline__ void gld16(const void* g, void* l) {
    // async global->LDS DMA: 16B per lane, LDS dest = wave-uniform base + lane*16
    __builtin_amdgcn_global_load_lds((const GAS void*)g, (LAS void*)l, 16, 0, 0);
}

__device__ __forceinline__ float wave_allreduce_sum(float v) {
    #pragma unroll
    for (int off = 32; off >= 1; off >>= 1) v += __shfl_xor(v, off);
    return v;
}

// ---------------- prep: w1 -> w1h (pad K to 800), w2 -> w2h (pad N to 1024), zero stats ----------
__global__ __launch_bounds__(256)
void prep_kernel(const float* __restrict__ w1, _Float16* __restrict__ w1h,
                 const float* __restrict__ w2, _Float16* __restrict__ w2h,
                 float* __restrict__ stat)
{
    const int tid = threadIdx.x;
    if (blockIdx.x == 0) {
        for (int j = tid; j < 1024 + 16; j += 256) stat[j] = 0.0f;   // sums/ssqs + zbuf
    }
    const int NW1 = HIDD * (KPAD1 / 8);     // 25600 granules
    const int NW2 = OUTDP * (HIDD / 8);     // 32768 granules
    for (int i = blockIdx.x * 256 + tid; i < NW1 + NW2; i += (int)gridDim.x * 256) {
        half8 o;
        if (i < NW1) {
            const int r = i / (KPAD1 / 8), c8 = (i % (KPAD1 / 8)) * 8;
            if (c8 + 8 <= IND) {
                const float* s = &w1[(size_t)r * IND + c8];
                float4 v0 = *(const float4*)s, v1 = *(const float4*)(s + 4);
                o[0]=(_Float16)v0.x; o[1]=(_Float16)v0.y; o[2]=(_Float16)v0.z; o[3]=(_Float16)v0.w;
                o[4]=(_Float16)v1.x; o[5]=(_Float16)v1.y; o[6]=(_Float16)v1.z; o[7]=(_Float16)v1.w;
            } else {
                #pragma unroll
                for (int j = 0; j < 8; ++j) o[j] = (_Float16)0.0f;
            }
            *(half8*)&w1h[(size_t)r * KPAD1 + c8] = o;
        } else {
            const int k = i - NW1;
            const int r = k >> 5, c8 = (k & 31) * 8;
            if (r < OUTD) {
                const float* s = &w2[(size_t)r * HIDD + c8];
                float4 v0 = *(const float4*)s, v1 = *(const float4*)(s + 4);
                o[0]=(_Float16)v0.x; o[1]=(_Float16)v0.y; o[2]=(_Float16)v0.z; o[3]=(_Float16)v0.w;
                o[4]=(_Float16)v1.x; o[5]=(_Float16)v1.y; o[6]=(_Float16)v1.z; o[7]=(_Float16)v1.w;
            } else {
                #pragma unroll
                for (int j = 0; j < 8; ++j) o[j] = (_Float16)0.0f;
            }
            *(half8*)&w2h[(size_t)r * HIDD + c8] = o;
        }
    }
}

// ================= GEMM1: h = x(fp32,K=784) @ w1h(fp16,K=800)^T + b1, BN1 stats =================
// Depth-3 pipeline: 3 LDS buffers, prefetch 2 tiles ahead, counted vmcnt(6) + raw barrier
// (loads never drained to 0 in the main loop). A staged fp32 with 3-bit XOR source swizzle,
// converted fp32->fp16 at fragment read; B fp16 with 2-bit XOR swizzle. Invalid tiles -> zbuf.
__global__ __launch_bounds__(256, 2)
void gemm1_kernel(const float* __restrict__ x, const _Float16* __restrict__ w1h,
                  const float* __restrict__ b1, const float* __restrict__ zbuf,
                  float* __restrict__ h, float* __restrict__ sum1, float* __restrict__ ssq1)
{
    __shared__ __align__(16) float    ldsA[3][4096];   // 3 x 16KB
    __shared__ __align__(16) _Float16 ldsB[3][4096];   // 3 x 8KB
    __shared__ float redS[2][128], redQ[2][128];

    const int tid  = threadIdx.x;
    const int bid0 = blockIdx.x;
    const int vbid = (bid0 & 7) * 64 + (bid0 >> 3);    // XCD chunking (grid 512)
    const int bm = vbid >> 1, bn = vbid & 1;
    const int m0 = bm * 128, n0 = bn * 128;
    const int lane = tid & 63, wv = tid >> 6;
    const int wr = wv >> 1, wc = wv & 1;
    const int l15 = lane & 15, lg = lane >> 4;
    const int e7 = l15 & 7, e3 = l15 & 3;
    const int nt = KPAD1 / 32;                          // 25

    // staging lane geometry (source pre-swizzled; LDS dest linear)
    const int arow = lane >> 3, agp = (lane & 7) ^ arow;        // fp32: granule = 4 floats
    const int brow = lane >> 2, bgp = (lane & 3) ^ (brow & 3);  // fp16: granule = 8 halves
    const float*    Ab = x   + (size_t)(m0 + arow) * IND   + agp * 4;
    const _Float16* Bb = w1h + (size_t)(n0 + brow) * KPAD1 + bgp * 8;

    floatx4 acc[4][4];
    #pragma unroll
    for (int i = 0; i < 4; ++i)
        #pragma unroll
        for (int j = 0; j < 4; ++j) acc[i][j] = (floatx4){0.f, 0.f, 0.f, 0.f};

    auto STAGE = [&](int buf, int t) {                  // 6 gld16 per thread, always
        const int t32 = t * 32;
        const bool tok = t < nt;
        const bool aok = tok && (t32 + agp * 4) < IND;
        #pragma unroll
        for (int c = 0; c < 4; ++c) {
            const int ch = wv + c * 4;                  // A chunks 0..15 (8 rows x 32k each)
            const float* s = aok ? (Ab + (size_t)ch * 8 * IND + t32) : zbuf;
            gld16(s, &ldsA[buf][ch * 256]);
        }
        #pragma unroll
        for (int c = 0; c < 2; ++c) {
            const int ch = wv + c * 4;                  // B chunks 0..7 (16 rows x 32k each)
            const void* s = tok ? (const void*)(Bb + (size_t)ch * 16 * KPAD1 + t32)
                                : (const void*)zbuf;
            gld16(s, &ldsB[buf][ch * 512]);
        }
    };

    STAGE(0, 0);
    STAGE(1, 1);
    WAITVM_BAR(6);                                      // tile0 resident; tile1 in flight

    int buf = 0;
    for (int t = 0; t < nt; ++t) {
        int nbuf = buf + 2; if (nbuf >= 3) nbuf -= 3;
        STAGE(nbuf, t + 2);                             // outstanding: t+1 (6) + t+2 (6)
        half8 af[4], bfr[4];
        #pragma unroll
        for (int i = 0; i < 4; ++i) {
            const int rc = wr * 8 + i * 2 + (l15 >> 3);
            const float* base = &ldsA[buf][rc * 256 + e7 * 32];
            float4 va = *(const float4*)(base + (((2 * lg)     ^ e7) * 4));
            float4 vb = *(const float4*)(base + (((2 * lg + 1) ^ e7) * 4));
            half8 hv;
            hv[0]=(_Float16)va.x; hv[1]=(_Float16)va.y; hv[2]=(_Float16)va.z; hv[3]=(_Float16)va.w;
            hv[4]=(_Float16)vb.x; hv[5]=(_Float16)vb.y; hv[6]=(_Float16)vb.z; hv[7]=(_Float16)vb.w;
            af[i] = hv;
        }
        #pragma unroll
        for (int j = 0; j < 4; ++j)
            bfr[j] = *(const half8*)&ldsB[buf][(wc * 4 + j) * 512 + l15 * 32 + ((lg ^ e3) * 8)];
        #pragma unroll
        for (int i = 0; i < 4; ++i)
            #pragma unroll
            for (int j = 0; j < 4; ++j)
                acc[i][j] = __builtin_amdgcn_mfma_f32_16x16x32_f16(bfr[j], af[i], acc[i][j], 0, 0, 0);
        WAITVM_BAR(6);                                  // t+1 retired; t+2 stays in flight
        buf = (buf + 1 == 3) ? 0 : buf + 1;
    }

    // epilogue: bias, float4 store, column stats (syncthreads below drains trailing loads)
    float sJ[4][4], qJ[4][4];
    #pragma unroll
    for (int j = 0; j < 4; ++j)
        #pragma unroll
        for (int r = 0; r < 4; ++r) { sJ[j][r] = 0.f; qJ[j][r] = 0.f; }
    #pragma unroll
    for (int i = 0; i < 4; ++i) {
        const int m = m0 + wr * 64 + i * 16 + l15;
        #pragma unroll
        for (int j = 0; j < 4; ++j) {
            const int nb = n0 + wc * 64 + j * 16 + lg * 4;
            float4 bt = *reinterpret_cast<const float4*>(&b1[nb]);
            float v[4] = {acc[i][j][0] + bt.x, acc[i][j][1] + bt.y,
                          acc[i][j][2] + bt.z, acc[i][j][3] + bt.w};
            *reinterpret_cast<float4*>(&h[(size_t)m * HIDD + nb]) =
                make_float4(v[0], v[1], v[2], v[3]);
            #pragma unroll
            for (int r = 0; r < 4; ++r) { sJ[j][r] += v[r]; qJ[j][r] += v[r] * v[r]; }
        }
    }
    #pragma unroll
    for (int j = 0; j < 4; ++j)
        #pragma unroll
        for (int r = 0; r < 4; ++r) {
            float s = sJ[j][r], q = qJ[j][r];
            s += __shfl_xor(s, 1); s += __shfl_xor(s, 2);
            s += __shfl_xor(s, 4); s += __shfl_xor(s, 8);
            q += __shfl_xor(q, 1); q += __shfl_xor(q, 2);
            q += __shfl_xor(q, 4); q += __shfl_xor(q, 8);
            if (l15 == 0) {
                redS[wr][wc * 64 + j * 16 + lg * 4 + r] = s;
                redQ[wr][wc * 64 + j * 16 + lg * 4 + r] = q;
            }
        }
    __syncthreads();
    if (tid < 128) {
        atomicAdd(&sum1[n0 + tid], redS[0][tid] + redS[1][tid]);
        atomicAdd(&ssq1[n0 + tid], redQ[0][tid] + redQ[1][tid]);
    }
}

// ---------------- middle: BN1 finalize -> relu(bn1(h)) -> log_map0 -> butterfly x3 ->
//                  exp_map0 -> ht16 (x65536) + BN2 raw stats ----------------
__global__ __launch_bounds__(256)
void mid_kernel(const float* __restrict__ h, const float* __restrict__ bfp,
                const float* __restrict__ sum1, const float* __restrict__ ssq1,
                const float* __restrict__ g1, const float* __restrict__ be1,
                _Float16* __restrict__ ht16, float* __restrict__ sum2, float* __restrict__ ssq2)
{
    __shared__ float s1sh[256], t1sh[256];
    __shared__ float bsum[4][256], bssq[4][256];
    const int tid  = threadIdx.x;
    {
        const float inv = 1.0f / (float)NBATCH;
        const float mu  = sum1[tid] * inv;
        const float var = fmaxf(ssq1[tid] * inv - mu * mu, 0.0f);
        const float rs  = 1.0f / sqrtf(var + 1e-5f);
        const float sj  = g1[tid] * rs;
        s1sh[tid] = sj;
        t1sh[tid] = fmaf(-mu, sj, be1[tid]);
    }
    __syncthreads();

    const int w    = tid >> 6;
    const int lane = tid & 63;
    const int row0 = blockIdx.x * 64 + w * 16;
    const int c0   = lane * 4;

    const float4 s1v = *reinterpret_cast<const float4*>(&s1sh[c0]);
    const float4 t1v = *reinterpret_cast<const float4*>(&t1sh[c0]);
    const float a0 = bfp[2 * lane],       a1 = bfp[2 * lane + 1];
    const float b0 = bfp[128 + 2 * lane], b1 = bfp[128 + 2 * lane + 1];
    const float a2 = bfp[256 + lane],     b2 = bfp[320 + lane];
    const float a3 = bfp[384 + (lane >> 1)], b3 = bfp[416 + (lane >> 1)];
    const float sgn = (lane & 1) ? -1.0f : 1.0f;
    const float sc  = sqrtf(1e-3f);

    float ps0 = 0, ps1 = 0, ps2 = 0, ps3 = 0;
    float q0 = 0, q1 = 0, q2 = 0, q3 = 0;

    for (int r = 0; r < 16; ++r) {
        const int row = row0 + r;
        const float4 v = *reinterpret_cast<const float4*>(&h[(size_t)row * HIDD + c0]);
        float x0 = fmaxf(fmaf(v.x, s1v.x, t1v.x), 0.0f);
        float x1 = fmaxf(fmaf(v.y, s1v.y, t1v.y), 0.0f);
        float x2 = fmaxf(fmaf(v.z, s1v.z, t1v.z), 0.0f);
        float x3 = fmaxf(fmaf(v.w, s1v.w, t1v.w), 0.0f);
        float n2 = x0 * x0 + x1 * x1 + x2 * x2 + x3 * x3;
        n2 = wave_allreduce_sum(n2);
        float sn = sc * sqrtf(n2);
        sn = fminf(fmaxf(sn, 1e-7f), 1.0f - 1e-6f);
        const float ls = atanhf(sn) / sn;
        x0 *= ls; x1 *= ls; x2 *= ls; x3 *= ls;
        const float y0 = fmaf(a0, x0,  b0 * x1);
        const float y1 = fmaf(a0, x1, -b0 * x0);
        const float y2 = fmaf(a1, x2,  b1 * x3);
        const float y3 = fmaf(a1, x3, -b1 * x2);
        const float z0 = fmaf(a2, y0,  b2 * y2);
        const float z1 = fmaf(a2, y1,  b2 * y3);
        const float z2 = fmaf(a2, y2, -b2 * y0);
        const float z3 = fmaf(a2, y3, -b2 * y1);
        const float p0 = __shfl_xor(z0, 1);
        const float p1 = __shfl_xor(z1, 1);
        const float p2 = __shfl_xor(z2, 1);
        const float p3 = __shfl_xor(z3, 1);
        const float w0 = fmaf(a3, z0, sgn * (b3 * p0));
        const float w1 = fmaf(a3, z1, sgn * (b3 * p1));
        const float w2 = fmaf(a3, z2, sgn * (b3 * p2));
        const float w3 = fmaf(a3, z3, sgn * (b3 * p3));
        float m2 = w0 * w0 + w1 * w1 + w2 * w2 + w3 * w3;
        m2 = wave_allreduce_sum(m2);
        const float sn2 = fmaxf(sc * sqrtf(m2), 1e-7f);
        const float es = tanhf(sn2) / sn2;
        const float o0 = es * w0, o1 = es * w1, o2 = es * w2, o3 = es * w3;
        half4v hv;
        hv[0] = (_Float16)(o0 * 65536.0f); hv[1] = (_Float16)(o1 * 65536.0f);
        hv[2] = (_Float16)(o2 * 65536.0f); hv[3] = (_Float16)(o3 * 65536.0f);
        *reinterpret_cast<half4v*>(&ht16[(size_t)row * HIDD + c0]) = hv;
        ps0 += o0; ps1 += o1; ps2 += o2; ps3 += o3;
        q0 += o0 * o0; q1 += o1 * o1; q2 += o2 * o2; q3 += o3 * o3;
    }

    bsum[w][c0 + 0] = ps0; bsum[w][c0 + 1] = ps1; bsum[w][c0 + 2] = ps2; bsum[w][c0 + 3] = ps3;
    bssq[w][c0 + 0] = q0;  bssq[w][c0 + 1] = q1;  bssq[w][c0 + 2] = q2;  bssq[w][c0 + 3] = q3;
    __syncthreads();
    if (tid < 256) {
        const float s = bsum[0][tid] + bsum[1][tid] + bsum[2][tid] + bsum[3][tid];
        const float q = bssq[0][tid] + bssq[1][tid] + bssq[2][tid] + bssq[3][tid];
        atomicAdd(&sum2[tid], s);
        atomicAdd(&ssq2[tid], q);
    }
}

// ================= GEMM2: out = relu(bn2(ht)) @ w2h^T + b2, BN2 fused at fragment read =========
// Depth-3 pipeline, counted vmcnt(4). A = ht16 (ht*65536); prologue finalizes BN2 into sf/tf
// (LDS writes are lgkmcnt-fenced by the first WAITVM_BAR before any cross-wave read).
__global__ __launch_bounds__(256, 3)
void gemm2_kernel(const _Float16* __restrict__ ht16, const _Float16* __restrict__ w2h,
                  const float* __restrict__ b2,
                  const float* __restrict__ sum2, const float* __restrict__ ssq2,
                  const float* __restrict__ g2, const float* __restrict__ be2,
                  const float* __restrict__ zbuf, float* __restrict__ out)
{
    __shared__ __align__(16) _Float16 ldsA[3][4096];   // 3 x 8KB
    __shared__ __align__(16) _Float16 ldsB[3][4096];
    __shared__ float sf[256], tf[256];

    const int tid = threadIdx.x;
    {
        const float inv = 1.0f / (float)NBATCH;
        const float mu  = sum2[tid] * inv;
        const float var = fmaxf(ssq2[tid] * inv - mu * mu, 0.0f);
        const float rs  = 1.0f / sqrtf(var + 1e-5f);
        const float sj  = g2[tid] * rs;
        sf[tid] = sj * (1024.0f / 65536.0f);
        tf[tid] = fmaf(-mu, sj, be2[tid]) * 1024.0f;
    }

    const int bid0 = blockIdx.x;
    const int vbid = (bid0 & 7) * 256 + (bid0 >> 3);   // XCD chunking (grid 2048)
    const int bm = vbid >> 3, bn = vbid & 7;
    const int m0 = bm * 128, n0 = bn * 128;
    const int lane = tid & 63, wv = tid >> 6;
    const int wr = wv >> 1, wc = wv & 1;
    const int l15 = lane & 15, lg = lane >> 4;
    const int e3 = l15 & 3;
    const int nt = HIDD / 32;                           // 8

    const int srow = lane >> 2, sgp = (lane & 3) ^ (srow & 3);
    const _Float16* Ab = ht16 + (size_t)(m0 + srow) * HIDD + sgp * 8;
    const _Float16* Bb = w2h  + (size_t)(n0 + srow) * HIDD + sgp * 8;

    floatx4 acc[4][4];
    #pragma unroll
    for (int i = 0; i < 4; ++i)
        #pragma unroll
        for (int j = 0; j < 4; ++j) acc[i][j] = (floatx4){0.f, 0.f, 0.f, 0.f};

    auto STAGE = [&](int buf, int t) {                  // 4 gld16 per thread, always
        const int t32 = t * 32;
        const bool tok = t < nt;
        #pragma unroll
        for (int c = 0; c < 2; ++c) {
            const int ch = wv + c * 4;                  // chunks 0..7 (16 rows x 32k)
            const void* sa = tok ? (const void*)(Ab + (size_t)ch * 16 * HIDD + t32)
                                 : (const void*)zbuf;
            const void* sb = tok ? (const void*)(Bb + (size_t)ch * 16 * HIDD + t32)
                                 : (const void*)zbuf;
            gld16(sa, &ldsA[buf][ch * 512]);
            gld16(sb, &ldsB[buf][ch * 512]);
        }
    };

    STAGE(0, 0);
    STAGE(1, 1);
    WAITVM_BAR(4);                                      // fences sf/tf (lgkmcnt(0)+barrier)

    int buf = 0;
    for (int t = 0; t < nt; ++t) {
        int nbuf = buf + 2; if (nbuf >= 3) nbuf -= 3;
        STAGE(nbuf, t + 2);
        const int kb = t * 32 + lg * 8;
        float4 s0 = *(const float4*)&sf[kb], s1 = *(const float4*)&sf[kb + 4];
        float4 t0 = *(const float4*)&tf[kb], t1 = *(const float4*)&tf[kb + 4];
        half8 af[4], bfr[4];
        #pragma unroll
        for (int i = 0; i < 4; ++i) {
            half8 v = *(const half8*)&ldsA[buf][(wr * 4 + i) * 512 + l15 * 32 + ((lg ^ e3) * 8)];
            half8 hv;
            hv[0] = (_Float16)fmaxf(fmaf((float)v[0], s0.x, t0.x), 0.0f);
            hv[1] = (_Float16)fmaxf(fmaf((float)v[1], s0.y, t0.y), 0.0f);
            hv[2] = (_Float16)fmaxf(fmaf((float)v[2], s0.z, t0.z), 0.0f);
            hv[3] = (_Float16)fmaxf(fmaf((float)v[3], s0.w, t0.w), 0.0f);
            hv[4] = (_Float16)fmaxf(fmaf((float)v[4], s1.x, t1.x), 0.0f);
            hv[5] = (_Float16)fmaxf(fmaf((float)v[5], s1.y, t1.y), 0.0f);
            hv[6] = (_Float16)fmaxf(fmaf((float)v[6], s1.z, t1.z), 0.0f);
            hv[7] = (_Float16)fmaxf(fmaf((float)v[7], s1.w, t1.w), 0.0f);
            af[i] = hv;
        }
        #pragma unroll
        for (int j = 0; j < 4; ++j)
            bfr[j] = *(const half8*)&ldsB[buf][(wc * 4 + j) * 512 + l15 * 32 + ((lg ^ e3) * 8)];
        #pragma unroll
        for (int i = 0; i < 4; ++i)
            #pragma unroll
            for (int j = 0; j < 4; ++j)
                acc[i][j] = __builtin_amdgcn_mfma_f32_16x16x32_f16(bfr[j], af[i], acc[i][j], 0, 0, 0);
        WAITVM_BAR(4);
        buf = (buf + 1 == 3) ? 0 : buf + 1;
    }
    asm volatile("s_waitcnt vmcnt(0)" ::: "memory");    // drain trailing zbuf loads

    // epilogue: /1024, + bias, bounds-checked float4 store (N=1000 < padded 1024)
    const float invScale = 1.0f / 1024.0f;
    #pragma unroll
    for (int i = 0; i < 4; ++i) {
        const int m = m0 + wr * 64 + i * 16 + l15;
        #pragma unroll
        for (int j = 0; j < 4; ++j) {
            const int nb = n0 + wc * 64 + j * 16 + lg * 4;
            float bj[4];
            if (nb + 4 <= OUTD) {
                float4 bt = *reinterpret_cast<const float4*>(&b2[nb]);
                bj[0] = bt.x; bj[1] = bt.y; bj[2] = bt.z; bj[3] = bt.w;
            } else {
                #pragma unroll
                for (int r = 0; r < 4; ++r) bj[r] = (nb + r < OUTD) ? b2[nb + r] : 0.0f;
            }
            float v[4];
            #pragma unroll
            for (int r = 0; r < 4; ++r) v[r] = fmaf(acc[i][j][r], invScale, bj[r]);
            if (nb + 4 <= OUTD) {
                *reinterpret_cast<float4*>(&out[(size_t)m * OUTD + nb]) =
                    make_float4(v[0], v[1], v[2], v[3]);
            } else {
                #pragma unroll
                for (int r = 0; r < 4; ++r)
                    if (nb + r < OUTD) out[(size_t)m * OUTD + nb + r] = v[r];
            }
        }
    }
}

extern "C" void kernel_launch(void* const* d_in, const int* in_sizes, int n_in,
                              void* d_out, int out_size, void* d_ws, size_t ws_size,
                              hipStream_t stream)
{
    const float* x   = (const float*)d_in[0];
    const float* w1  = (const float*)d_in[1];
    const float* b1  = (const float*)d_in[2];
    const float* g1  = (const float*)d_in[3];
    const float* be1 = (const float*)d_in[4];
    const float* bfp = (const float*)d_in[5];
    const float* g2  = (const float*)d_in[6];
    const float* be2 = (const float*)d_in[7];
    const float* w2  = (const float*)d_in[8];
    const float* b2  = (const float*)d_in[9];

    float* out = (float*)d_out;
    char*  wsb = (char*)d_ws;

    // ws layout (all 16B aligned): ht16 | w1h | w2h | stats+zbuf   (~17.7 MB)
    _Float16* ht16 = (_Float16*)(wsb);                    // 32768 x 256 fp16
    _Float16* w1h  = (_Float16*)(wsb + 16777216);         //   256 x 800 fp16
    _Float16* w2h  = (_Float16*)(wsb + 17186816);         //  1024 x 256 fp16
    float*    stat = (float*)  (wsb + 17711104);          // 4 x 256 stats + 16 zbuf
    float* sum1 = stat;
    float* ssq1 = stat + 256;
    float* sum2 = stat + 512;
    float* ssq2 = stat + 768;
    float* zbuf = stat + 1024;

    float* h = out;   // park h[32768][256] fp32 in d_out; consumed by mid before GEMM2 overwrites

    // 1) weight conversion + stats zeroing
    prep_kernel<<<232, 256, 0, stream>>>(w1, w1h, w2, w2h, stat);
    // 2) GEMM1 (direct fp32 x staging, depth-3 counted-vmcnt pipeline) + BN1 stats
    gemm1_kernel<<<512, 256, 0, stream>>>(x, w1h, b1, zbuf, h, sum1, ssq1);
    // 3) BN1 finalize + relu + log-map + butterfly x3 + exp-map -> ht16, BN2 stats
    mid_kernel<<<512, 256, 0, stream>>>(h, bfp, sum1, ssq1, g1, be1, ht16, sum2, ssq2);
    // 4) GEMM2 with fused BN2+relu at fragment read (depth-3 counted-vmcnt pipeline)
    gemm2_kernel<<<2048, 256, 0, stream>>>(ht16, w2h, b2, sum2, ssq2, g2, be2, zbuf, out);
}

// Round 9
// 126.443 us; speedup vs baseline: 3.5568x; 1.0233x over previous
//
#include <hip/hip_runtime.h>
#include <math.h>

#define NBATCH 32768
#define IND    784
#define KPAD1  800
#define HIDD   256
#define OUTD   1000
#define OUTDP  1024

typedef _Float16 half8  __attribute__((ext_vector_type(8)));
typedef _Float16 half4v __attribute__((ext_vector_type(4)));
typedef float    floatx4 __attribute__((ext_vector_type(4)));

#define GAS __attribute__((address_space(1)))
#define LAS __attribute__((address_space(3)))

#define WAITVM(N) asm volatile("s_waitcnt vmcnt(" #N ")" ::: "memory")
// counted-vmcnt + lgkmcnt(0) (raw s_barrier does NOT fence LDS ops) + barrier + sched pin
#define WAITVM_BAR(N)                                                      \
    asm volatile("s_waitcnt vmcnt(" #N ") lgkmcnt(0)" ::: "memory");       \
    __builtin_amdgcn_s_barrier();                                          \
    __builtin_amdgcn_sched_barrier(0)

__device__ __forceinline__ void gld16(const void* g, void* l) {
    // async global->LDS DMA: 16B per lane, LDS dest = wave-uniform base + lane*16
    __builtin_amdgcn_global_load_lds((const GAS void*)g, (LAS void*)l, 16, 0, 0);
}

__device__ __forceinline__ float wave_allreduce_sum(float v) {
    #pragma unroll
    for (int off = 32; off >= 1; off >>= 1) v += __shfl_xor(v, off);
    return v;
}

// ---------------- prep: w1 -> w1h (pad K to 800), w2 -> w2h (pad N to 1024), zero stats ----------
__global__ __launch_bounds__(256)
void prep_kernel(const float* __restrict__ w1, _Float16* __restrict__ w1h,
                 const float* __restrict__ w2, _Float16* __restrict__ w2h,
                 float* __restrict__ stat)
{
    const int tid = threadIdx.x;
    if (blockIdx.x == 0) {
        for (int j = tid; j < 1024 + 16; j += 256) stat[j] = 0.0f;   // sums/ssqs + zbuf
    }
    const int NW1 = HIDD * (KPAD1 / 8);     // 25600 granules
    const int NW2 = OUTDP * (HIDD / 8);     // 32768 granules
    for (int i = blockIdx.x * 256 + tid; i < NW1 + NW2; i += (int)gridDim.x * 256) {
        half8 o;
        if (i < NW1) {
            const int r = i / (KPAD1 / 8), c8 = (i % (KPAD1 / 8)) * 8;
            if (c8 + 8 <= IND) {
                const float* s = &w1[(size_t)r * IND + c8];
                float4 v0 = *(const float4*)s, v1 = *(const float4*)(s + 4);
                o[0]=(_Float16)v0.x; o[1]=(_Float16)v0.y; o[2]=(_Float16)v0.z; o[3]=(_Float16)v0.w;
                o[4]=(_Float16)v1.x; o[5]=(_Float16)v1.y; o[6]=(_Float16)v1.z; o[7]=(_Float16)v1.w;
            } else {
                #pragma unroll
                for (int j = 0; j < 8; ++j) o[j] = (_Float16)0.0f;
            }
            *(half8*)&w1h[(size_t)r * KPAD1 + c8] = o;
        } else {
            const int k = i - NW1;
            const int r = k >> 5, c8 = (k & 31) * 8;
            if (r < OUTD) {
                const float* s = &w2[(size_t)r * HIDD + c8];
                float4 v0 = *(const float4*)s, v1 = *(const float4*)(s + 4);
                o[0]=(_Float16)v0.x; o[1]=(_Float16)v0.y; o[2]=(_Float16)v0.z; o[3]=(_Float16)v0.w;
                o[4]=(_Float16)v1.x; o[5]=(_Float16)v1.y; o[6]=(_Float16)v1.z; o[7]=(_Float16)v1.w;
            } else {
                #pragma unroll
                for (int j = 0; j < 8; ++j) o[j] = (_Float16)0.0f;
            }
            *(half8*)&w2h[(size_t)r * HIDD + c8] = o;
        }
    }
}

// ================= GEMM1: h = x(fp32) @ w1h(fp16)^T + b1, BN1 stats =================
// A: REG-STAGED to fp16 (T14): 4x dwordx4 issued ~1.5 iters early -> cvt -> 2x ds_write_b128
//    just before the barrier. LDS A = fp16 [2][128][32] (+in-row XOR swizzle).
// B: gld16 DMA, fp16, 3 buffers.  Single barrier/iter, counted vmcnt(6) (= 4 A-loads + 2 B-DMA).
// 42KB LDS -> 3 blocks/CU (12 waves/CU).
__global__ __launch_bounds__(256, 3)
void gemm1_kernel(const float* __restrict__ x, const _Float16* __restrict__ w1h,
                  const float* __restrict__ b1, const float* __restrict__ zbuf,
                  float* __restrict__ h, float* __restrict__ sum1, float* __restrict__ ssq1)
{
    __shared__ __align__(16) _Float16 ldsA[2][4096];   // 2 x 8KB
    __shared__ __align__(16) _Float16 ldsB[3][4096];   // 3 x 8KB
    __shared__ float redS[2][128], redQ[2][128];

    const int tid  = threadIdx.x;
    const int bid0 = blockIdx.x;
    const int vbid = (bid0 & 7) * 64 + (bid0 >> 3);    // XCD chunking (grid 512)
    const int bm = vbid >> 1, bn = vbid & 1;
    const int m0 = bm * 128, n0 = bn * 128;
    const int lane = tid & 63, wv = tid >> 6;
    const int wr = wv >> 1, wc = wv & 1;
    const int l15 = lane & 15, lg = lane >> 4;
    const int e3 = l15 & 3;
    const int nt = KPAD1 / 32;                          // 25

    // A reg-staging geometry: granule g = c*256+tid -> row g>>2, kq g&3 (8 k-floats)
    const int r0g = tid >> 2;            // rows 0..63   (c=0)
    const int r1g = 64 + (tid >> 2);     // rows 64..127 (c=1)
    const int kq  = tid & 3;
    const int wpos0 = r0g * 32 + ((kq ^ (r0g & 3)) * 8);   // swizzled LDS pos (halves)
    const int wpos1 = r1g * 32 + ((kq ^ (r1g & 3)) * 8);
    const float* Ab0 = x + (size_t)(m0 + r0g) * IND + kq * 8;
    const float* Ab1 = x + (size_t)(m0 + r1g) * IND + kq * 8;

    // B staging (DMA): granule=lane, row=lane>>2, source kq pre-swizzled
    const int brow = lane >> 2, bgp = (lane & 3) ^ (brow & 3);
    const _Float16* Bb = w1h + (size_t)(n0 + brow) * KPAD1 + bgp * 8;

    floatx4 acc[4][4];
    #pragma unroll
    for (int i = 0; i < 4; ++i)
        #pragma unroll
        for (int j = 0; j < 4; ++j) acc[i][j] = (floatx4){0.f, 0.f, 0.f, 0.f};

    floatx4 rgaE[4], rgaO[4];   // two named reg sets (even/odd tiles) — no runtime indexing

    auto A_ISSUE = [&](floatx4 (&rg)[4], int t) {       // 4 global_load_dwordx4
        const int t32 = t * 32;
        const bool v = (t32 + kq * 8) < IND;            // IND % 8 == 0
        const float* p0 = v ? (Ab0 + t32) : zbuf;
        const float* p1 = v ? (Ab1 + t32) : zbuf;
        rg[0] = *(const floatx4*)p0;
        rg[1] = *(const floatx4*)(p0 + 4);
        rg[2] = *(const floatx4*)p1;
        rg[3] = *(const floatx4*)(p1 + 4);
    };
    auto A_WRITE = [&](floatx4 (&rg)[4], int wb) {      // cvt + 2 ds_write_b128
        half8 h0, h1;
        #pragma unroll
        for (int j = 0; j < 4; ++j) {
            h0[j] = (_Float16)rg[0][j]; h0[4 + j] = (_Float16)rg[1][j];
            h1[j] = (_Float16)rg[2][j]; h1[4 + j] = (_Float16)rg[3][j];
        }
        *(half8*)&ldsA[wb][wpos0] = h0;
        *(half8*)&ldsA[wb][wpos1] = h1;
    };
    auto B_ISSUE = [&](int bb, int t) {                 // 2 gld16
        const int t32 = t * 32;
        const bool tok = t < nt;
        #pragma unroll
        for (int c = 0; c < 2; ++c) {
            const int ch = wv + c * 4;
            const void* s = tok ? (const void*)(Bb + (size_t)ch * 16 * KPAD1 + t32)
                                : (const void*)zbuf;
            gld16(s, &ldsB[bb][ch * 512]);
        }
    };

    auto COMPUTE = [&](int abuf, int brd) {
        half8 af[4], bfr[4];
        #pragma unroll
        for (int i = 0; i < 4; ++i)
            af[i] = *(const half8*)&ldsA[abuf][(wr * 64 + i * 16 + l15) * 32 + ((lg ^ e3) * 8)];
        #pragma unroll
        for (int j = 0; j < 4; ++j)
            bfr[j] = *(const half8*)&ldsB[brd][(wc * 4 + j) * 512 + l15 * 32 + ((lg ^ e3) * 8)];
        #pragma unroll
        for (int i = 0; i < 4; ++i)
            #pragma unroll
            for (int j = 0; j < 4; ++j)
                acc[i][j] = __builtin_amdgcn_mfma_f32_16x16x32_f16(bfr[j], af[i], acc[i][j], 0, 0, 0);
    };

    // ---- prologue: tile0 -> LDS (A via regs, B via DMA); tile1 in flight ----
    A_ISSUE(rgaE, 0); B_ISSUE(0, 0);
    WAITVM(2);                       // A(0) regs arrived (compiler also enforces reg deps)
    A_WRITE(rgaE, 0);
    A_ISSUE(rgaO, 1); B_ISSUE(1, 1);
    WAITVM_BAR(6);                   // B(0) resident; A(0) ds_writes fenced; barrier

    // ---- main loop: 12 pairs (t=0..23), tile t in ldsA[t&1]/ldsB[t%3] ----
    int b0 = 0;
    for (int p = 0; p < 12; ++p) {
        const int t  = p * 2;
        const int b1v = b0 + 1 == 3 ? 0 : b0 + 1;
        const int b2v = b1v + 1 == 3 ? 0 : b1v + 1;
        // even iter: compute t (A buf0), issue t+2 -> rgaE/ldsB[b2], write A(t+1) from rgaO
        A_ISSUE(rgaE, t + 2);
        B_ISSUE(b2v, t + 2);
        COMPUTE(0, b0);
        __builtin_amdgcn_sched_barrier(0);
        WAITVM(6);
        A_WRITE(rgaO, 1);
        WAITVM_BAR(6);
        // odd iter: compute t+1 (A buf1), issue t+3 -> rgaO/ldsB[b0], write A(t+2) from rgaE
        A_ISSUE(rgaO, t + 3);
        B_ISSUE(b0, t + 3);
        COMPUTE(1, b1v);
        __builtin_amdgcn_sched_barrier(0);
        WAITVM(6);
        A_WRITE(rgaE, 0);
        WAITVM_BAR(6);
        b0 = b2v;
    }
    // ---- final iteration t=24 (tile resident; only zbuf loads outstanding) ----
    COMPUTE(0, b0);
    WAITVM(0);                       // drain trailing zbuf loads

    // ---- epilogue: bias, float4 store, column stats ----
    float sJ[4][4], qJ[4][4];
    #pragma unroll
    for (int j = 0; j < 4; ++j)
        #pragma unroll
        for (int r = 0; r < 4; ++r) { sJ[j][r] = 0.f; qJ[j][r] = 0.f; }
    #pragma unroll
    for (int i = 0; i < 4; ++i) {
        const int m = m0 + wr * 64 + i * 16 + l15;
        #pragma unroll
        for (int j = 0; j < 4; ++j) {
            const int nb = n0 + wc * 64 + j * 16 + lg * 4;
            float4 bt = *reinterpret_cast<const float4*>(&b1[nb]);
            float v[4] = {acc[i][j][0] + bt.x, acc[i][j][1] + bt.y,
                          acc[i][j][2] + bt.z, acc[i][j][3] + bt.w};
            *reinterpret_cast<float4*>(&h[(size_t)m * HIDD + nb]) =
                make_float4(v[0], v[1], v[2], v[3]);
            #pragma unroll
            for (int r = 0; r < 4; ++r) { sJ[j][r] += v[r]; qJ[j][r] += v[r] * v[r]; }
        }
    }
    #pragma unroll
    for (int j = 0; j < 4; ++j)
        #pragma unroll
        for (int r = 0; r < 4; ++r) {
            float s = sJ[j][r], q = qJ[j][r];
            s += __shfl_xor(s, 1); s += __shfl_xor(s, 2);
            s += __shfl_xor(s, 4); s += __shfl_xor(s, 8);
            q += __shfl_xor(q, 1); q += __shfl_xor(q, 2);
            q += __shfl_xor(q, 4); q += __shfl_xor(q, 8);
            if (l15 == 0) {
                redS[wr][wc * 64 + j * 16 + lg * 4 + r] = s;
                redQ[wr][wc * 64 + j * 16 + lg * 4 + r] = q;
            }
        }
    __syncthreads();
    if (tid < 128) {
        atomicAdd(&sum1[n0 + tid], redS[0][tid] + redS[1][tid]);
        atomicAdd(&ssq1[n0 + tid], redQ[0][tid] + redQ[1][tid]);
    }
}

// ---------------- middle: BN1 finalize -> relu(bn1(h)) -> log_map0 -> butterfly x3 ->
//                  exp_map0 -> ht16 (x65536) + BN2 raw stats ----------------
__global__ __launch_bounds__(256)
void mid_kernel(const float* __restrict__ h, const float* __restrict__ bfp,
                const float* __restrict__ sum1, const float* __restrict__ ssq1,
                const float* __restrict__ g1, const float* __restrict__ be1,
                _Float16* __restrict__ ht16, float* __restrict__ sum2, float* __restrict__ ssq2)
{
    __shared__ float s1sh[256], t1sh[256];
    __shared__ float bsum[4][256], bssq[4][256];
    const int tid  = threadIdx.x;
    {
        const float inv = 1.0f / (float)NBATCH;
        const float mu  = sum1[tid] * inv;
        const float var = fmaxf(ssq1[tid] * inv - mu * mu, 0.0f);
        const float rs  = 1.0f / sqrtf(var + 1e-5f);
        const float sj  = g1[tid] * rs;
        s1sh[tid] = sj;
        t1sh[tid] = fmaf(-mu, sj, be1[tid]);
    }
    __syncthreads();

    const int w    = tid >> 6;
    const int lane = tid & 63;
    const int row0 = blockIdx.x * 64 + w * 16;
    const int c0   = lane * 4;

    const float4 s1v = *reinterpret_cast<const float4*>(&s1sh[c0]);
    const float4 t1v = *reinterpret_cast<const float4*>(&t1sh[c0]);
    const float a0 = bfp[2 * lane],       a1 = bfp[2 * lane + 1];
    const float b0 = bfp[128 + 2 * lane], b1 = bfp[128 + 2 * lane + 1];
    const float a2 = bfp[256 + lane],     b2 = bfp[320 + lane];
    const float a3 = bfp[384 + (lane >> 1)], b3 = bfp[416 + (lane >> 1)];
    const float sgn = (lane & 1) ? -1.0f : 1.0f;
    const float sc  = sqrtf(1e-3f);

    float ps0 = 0, ps1 = 0, ps2 = 0, ps3 = 0;
    float q0 = 0, q1 = 0, q2 = 0, q3 = 0;

    for (int r = 0; r < 16; ++r) {
        const int row = row0 + r;
        const float4 v = *reinterpret_cast<const float4*>(&h[(size_t)row * HIDD + c0]);
        float x0 = fmaxf(fmaf(v.x, s1v.x, t1v.x), 0.0f);
        float x1 = fmaxf(fmaf(v.y, s1v.y, t1v.y), 0.0f);
        float x2 = fmaxf(fmaf(v.z, s1v.z, t1v.z), 0.0f);
        float x3 = fmaxf(fmaf(v.w, s1v.w, t1v.w), 0.0f);
        float n2 = x0 * x0 + x1 * x1 + x2 * x2 + x3 * x3;
        n2 = wave_allreduce_sum(n2);
        float sn = sc * sqrtf(n2);
        sn = fminf(fmaxf(sn, 1e-7f), 1.0f - 1e-6f);
        const float ls = atanhf(sn) / sn;
        x0 *= ls; x1 *= ls; x2 *= ls; x3 *= ls;
        const float y0 = fmaf(a0, x0,  b0 * x1);
        const float y1 = fmaf(a0, x1, -b0 * x0);
        const float y2 = fmaf(a1, x2,  b1 * x3);
        const float y3 = fmaf(a1, x3, -b1 * x2);
        const float z0 = fmaf(a2, y0,  b2 * y2);
        const float z1 = fmaf(a2, y1,  b2 * y3);
        const float z2 = fmaf(a2, y2, -b2 * y0);
        const float z3 = fmaf(a2, y3, -b2 * y1);
        const float p0 = __shfl_xor(z0, 1);
        const float p1 = __shfl_xor(z1, 1);
        const float p2 = __shfl_xor(z2, 1);
        const float p3 = __shfl_xor(z3, 1);
        const float w0 = fmaf(a3, z0, sgn * (b3 * p0));
        const float w1 = fmaf(a3, z1, sgn * (b3 * p1));
        const float w2 = fmaf(a3, z2, sgn * (b3 * p2));
        const float w3 = fmaf(a3, z3, sgn * (b3 * p3));
        float m2 = w0 * w0 + w1 * w1 + w2 * w2 + w3 * w3;
        m2 = wave_allreduce_sum(m2);
        const float sn2 = fmaxf(sc * sqrtf(m2), 1e-7f);
        const float es = tanhf(sn2) / sn2;
        const float o0 = es * w0, o1 = es * w1, o2 = es * w2, o3 = es * w3;
        half4v hv;
        hv[0] = (_Float16)(o0 * 65536.0f); hv[1] = (_Float16)(o1 * 65536.0f);
        hv[2] = (_Float16)(o2 * 65536.0f); hv[3] = (_Float16)(o3 * 65536.0f);
        *reinterpret_cast<half4v*>(&ht16[(size_t)row * HIDD + c0]) = hv;
        ps0 += o0; ps1 += o1; ps2 += o2; ps3 += o3;
        q0 += o0 * o0; q1 += o1 * o1; q2 += o2 * o2; q3 += o3 * o3;
    }

    bsum[w][c0 + 0] = ps0; bsum[w][c0 + 1] = ps1; bsum[w][c0 + 2] = ps2; bsum[w][c0 + 3] = ps3;
    bssq[w][c0 + 0] = q0;  bssq[w][c0 + 1] = q1;  bssq[w][c0 + 2] = q2;  bssq[w][c0 + 3] = q3;
    __syncthreads();
    if (tid < 256) {
        const float s = bsum[0][tid] + bsum[1][tid] + bsum[2][tid] + bsum[3][tid];
        const float q = bssq[0][tid] + bssq[1][tid] + bssq[2][tid] + bssq[3][tid];
        atomicAdd(&sum2[tid], s);
        atomicAdd(&ssq2[tid], q);
    }
}

// ================= GEMM2: out = relu(bn2(ht)) @ w2h^T + b2, BN2 fused at fragment read =========
// Depth-3 DMA pipeline, counted vmcnt(4). A = ht16 (ht*65536); prologue finalizes BN2 into sf/tf.
__global__ __launch_bounds__(256, 3)
void gemm2_kernel(const _Float16* __restrict__ ht16, const _Float16* __restrict__ w2h,
                  const float* __restrict__ b2,
                  const float* __restrict__ sum2, const float* __restrict__ ssq2,
                  const float* __restrict__ g2, const float* __restrict__ be2,
                  const float* __restrict__ zbuf, float* __restrict__ out)
{
    __shared__ __align__(16) _Float16 ldsA[3][4096];   // 3 x 8KB
    __shared__ __align__(16) _Float16 ldsB[3][4096];
    __shared__ float sf[256], tf[256];

    const int tid = threadIdx.x;
    {
        const float inv = 1.0f / (float)NBATCH;
        const float mu  = sum2[tid] * inv;
        const float var = fmaxf(ssq2[tid] * inv - mu * mu, 0.0f);
        const float rs  = 1.0f / sqrtf(var + 1e-5f);
        const float sj  = g2[tid] * rs;
        sf[tid] = sj * (1024.0f / 65536.0f);
        tf[tid] = fmaf(-mu, sj, be2[tid]) * 1024.0f;
    }

    const int bid0 = blockIdx.x;
    const int vbid = (bid0 & 7) * 256 + (bid0 >> 3);   // XCD chunking (grid 2048)
    const int bm = vbid >> 3, bn = vbid & 7;
    const int m0 = bm * 128, n0 = bn * 128;
    const int lane = tid & 63, wv = tid >> 6;
    const int wr = wv >> 1, wc = wv & 1;
    const int l15 = lane & 15, lg = lane >> 4;
    const int e3 = l15 & 3;
    const int nt = HIDD / 32;                           // 8

    const int srow = lane >> 2, sgp = (lane & 3) ^ (srow & 3);
    const _Float16* Ab = ht16 + (size_t)(m0 + srow) * HIDD + sgp * 8;
    const _Float16* Bb = w2h  + (size_t)(n0 + srow) * HIDD + sgp * 8;

    floatx4 acc[4][4];
    #pragma unroll
    for (int i = 0; i < 4; ++i)
        #pragma unroll
        for (int j = 0; j < 4; ++j) acc[i][j] = (floatx4){0.f, 0.f, 0.f, 0.f};

    auto STAGE = [&](int buf, int t) {                  // 4 gld16 per thread, always
        const int t32 = t * 32;
        const bool tok = t < nt;
        #pragma unroll
        for (int c = 0; c < 2; ++c) {
            const int ch = wv + c * 4;                  // chunks 0..7 (16 rows x 32k)
            const void* sa = tok ? (const void*)(Ab + (size_t)ch * 16 * HIDD + t32)
                                 : (const void*)zbuf;
            const void* sb = tok ? (const void*)(Bb + (size_t)ch * 16 * HIDD + t32)
                                 : (const void*)zbuf;
            gld16(sa, &ldsA[buf][ch * 512]);
            gld16(sb, &ldsB[buf][ch * 512]);
        }
    };

    STAGE(0, 0);
    STAGE(1, 1);
    WAITVM_BAR(4);                                      // fences sf/tf (lgkmcnt(0)+barrier)

    int buf = 0;
    for (int t = 0; t < nt; ++t) {
        int nbuf = buf + 2; if (nbuf >= 3) nbuf -= 3;
        STAGE(nbuf, t + 2);
        const int kb = t * 32 + lg * 8;
        float4 s0 = *(const float4*)&sf[kb], s1 = *(const float4*)&sf[kb + 4];
        float4 t0 = *(const float4*)&tf[kb], t1 = *(const float4*)&tf[kb + 4];
        half8 af[4], bfr[4];
        #pragma unroll
        for (int i = 0; i < 4; ++i) {
            half8 v = *(const half8*)&ldsA[buf][(wr * 4 + i) * 512 + l15 * 32 + ((lg ^ e3) * 8)];
            half8 hv;
            hv[0] = (_Float16)fmaxf(fmaf((float)v[0], s0.x, t0.x), 0.0f);
            hv[1] = (_Float16)fmaxf(fmaf((float)v[1], s0.y, t0.y), 0.0f);
            hv[2] = (_Float16)fmaxf(fmaf((float)v[2], s0.z, t0.z), 0.0f);
            hv[3] = (_Float16)fmaxf(fmaf((float)v[3], s0.w, t0.w), 0.0f);
            hv[4] = (_Float16)fmaxf(fmaf((float)v[4], s1.x, t1.x), 0.0f);
            hv[5] = (_Float16)fmaxf(fmaf((float)v[5], s1.y, t1.y), 0.0f);
            hv[6] = (_Float16)fmaxf(fmaf((float)v[6], s1.z, t1.z), 0.0f);
            hv[7] = (_Float16)fmaxf(fmaf((float)v[7], s1.w, t1.w), 0.0f);
            af[i] = hv;
        }
        #pragma unroll
        for (int j = 0; j < 4; ++j)
            bfr[j] = *(const half8*)&ldsB[buf][(wc * 4 + j) * 512 + l15 * 32 + ((lg ^ e3) * 8)];
        #pragma unroll
        for (int i = 0; i < 4; ++i)
            #pragma unroll
            for (int j = 0; j < 4; ++j)
                acc[i][j] = __builtin_amdgcn_mfma_f32_16x16x32_f16(bfr[j], af[i], acc[i][j], 0, 0, 0);
        WAITVM_BAR(4);
        buf = (buf + 1 == 3) ? 0 : buf + 1;
    }
    WAITVM(0);                                          // drain trailing zbuf loads

    // epilogue: /1024, + bias, bounds-checked float4 store (N=1000 < padded 1024)
    const float invScale = 1.0f / 1024.0f;
    #pragma unroll
    for (int i = 0; i < 4; ++i) {
        const int m = m0 + wr * 64 + i * 16 + l15;
        #pragma unroll
        for (int j = 0; j < 4; ++j) {
            const int nb = n0 + wc * 64 + j * 16 + lg * 4;
            float bj[4];
            if (nb + 4 <= OUTD) {
                float4 bt = *reinterpret_cast<const float4*>(&b2[nb]);
                bj[0] = bt.x; bj[1] = bt.y; bj[2] = bt.z; bj[3] = bt.w;
            } else {
                #pragma unroll
                for (int r = 0; r < 4; ++r) bj[r] = (nb + r < OUTD) ? b2[nb + r] : 0.0f;
            }
            float v[4];
            #pragma unroll
            for (int r = 0; r < 4; ++r) v[r] = fmaf(acc[i][j][r], invScale, bj[r]);
            if (nb + 4 <= OUTD) {
                *reinterpret_cast<float4*>(&out[(size_t)m * OUTD + nb]) =
                    make_float4(v[0], v[1], v[2], v[3]);
            } else {
                #pragma unroll
                for (int r = 0; r < 4; ++r)
                    if (nb + r < OUTD) out[(size_t)m * OUTD + nb + r] = v[r];
            }
        }
    }
}

extern "C" void kernel_launch(void* const* d_in, const int* in_sizes, int n_in,
                              void* d_out, int out_size, void* d_ws, size_t ws_size,
                              hipStream_t stream)
{
    const float* x   = (const float*)d_in[0];
    const float* w1  = (const float*)d_in[1];
    const float* b1  = (const float*)d_in[2];
    const float* g1  = (const float*)d_in[3];
    const float* be1 = (const float*)d_in[4];
    const float* bfp = (const float*)d_in[5];
    const float* g2  = (const float*)d_in[6];
    const float* be2 = (const float*)d_in[7];
    const float* w2  = (const float*)d_in[8];
    const float* b2  = (const float*)d_in[9];

    float* out = (float*)d_out;
    char*  wsb = (char*)d_ws;

    // ws layout (all 16B aligned): ht16 | w1h | w2h | stats+zbuf   (~17.7 MB)
    _Float16* ht16 = (_Float16*)(wsb);                    // 32768 x 256 fp16
    _Float16* w1h  = (_Float16*)(wsb + 16777216);         //   256 x 800 fp16
    _Float16* w2h  = (_Float16*)(wsb + 17186816);         //  1024 x 256 fp16
    float*    stat = (float*)  (wsb + 17711104);          // 4 x 256 stats + 16 zbuf
    float* sum1 = stat;
    float* ssq1 = stat + 256;
    float* sum2 = stat + 512;
    float* ssq2 = stat + 768;
    float* zbuf = stat + 1024;

    float* h = out;   // park h[32768][256] fp32 in d_out; consumed by mid before GEMM2 overwrites

    // 1) weight conversion + stats zeroing
    prep_kernel<<<232, 256, 0, stream>>>(w1, w1h, w2, w2h, stat);
    // 2) GEMM1 (reg-staged fp16 A, single-barrier counted-vmcnt pipeline) + BN1 stats
    gemm1_kernel<<<512, 256, 0, stream>>>(x, w1h, b1, zbuf, h, sum1, ssq1);
    // 3) BN1 finalize + relu + log-map + butterfly x3 + exp-map -> ht16, BN2 stats
    mid_kernel<<<512, 256, 0, stream>>>(h, bfp, sum1, ssq1, g1, be1, ht16, sum2, ssq2);
    // 4) GEMM2 with fused BN2+relu at fragment read (depth-3 counted-vmcnt pipeline)
    gemm2_kernel<<<2048, 256, 0, stream>>>(ht16, w2h, b2, sum2, ssq2, g2, be2, zbuf, out);
}